// Round 3
// baseline (3243.808 us; speedup 1.0000x reference)
//
#include <hip/hip_runtime.h>
#include <hip/hip_bf16.h>

#define BB 4
#define NN 196
#define CC 13
#define DD 768
#define HH 12
#define HD 64
#define RR (BB*NN*CC)      /* 10192 */
#define E5 (5*DD)          /* 3840  */
#define NCH (NN*CC)        /* 2548  */

typedef __hip_bfloat16 bf16;
typedef __attribute__((ext_vector_type(4))) unsigned short us4;
typedef __attribute__((ext_vector_type(8))) unsigned short us8;

static __device__ __forceinline__ float4 ld4(const float* p){ return *(const float4*)p; }
static __device__ __forceinline__ float bf2f(unsigned short u){ return __uint_as_float(((unsigned)u)<<16); }

// ---------------------------------------------------------------------------
// QKV GEMM: C(bf16) = A(fp32) * B(fp32)^T.  A: MxK, B: NdxK row-major.
// Tile 64x64, BK=32, 256 threads, 4x4 per thread.
// ---------------------------------------------------------------------------
__global__ __launch_bounds__(256) void gemm_qkv(const float* __restrict__ A,
    const float* __restrict__ Bm, bf16* __restrict__ Cm, int M, int Nd, int K)
{
  __shared__ float As[64][33];
  __shared__ float Bs[64][33];
  const int m0 = blockIdx.y * 64, n0 = blockIdx.x * 64;
  const int tid = threadIdx.x;
  const int tr = tid >> 4, tc = tid & 15;
  float acc[4][4] = {};
  for (int k0 = 0; k0 < K; k0 += 32) {
    for (int i = tid; i < 64*8; i += 256) {
      int r = i >> 3, cq = i & 7;
      int gr = m0 + r;
      float4 v = make_float4(0.f,0.f,0.f,0.f);
      if (gr < M) v = ld4(&A[(size_t)gr*K + k0 + cq*4]);
      As[r][cq*4+0]=v.x; As[r][cq*4+1]=v.y; As[r][cq*4+2]=v.z; As[r][cq*4+3]=v.w;
    }
    for (int i = tid; i < 64*8; i += 256) {
      int r = i >> 3, cq = i & 7;
      int gr = n0 + r;
      float4 v = make_float4(0.f,0.f,0.f,0.f);
      if (gr < Nd) v = ld4(&Bm[(size_t)gr*K + k0 + cq*4]);
      Bs[r][cq*4+0]=v.x; Bs[r][cq*4+1]=v.y; Bs[r][cq*4+2]=v.z; Bs[r][cq*4+3]=v.w;
    }
    __syncthreads();
    #pragma unroll
    for (int kk = 0; kk < 32; kk++) {
      float a[4], bv[4];
      #pragma unroll
      for (int i = 0; i < 4; i++) a[i] = As[tr*4+i][kk];
      #pragma unroll
      for (int j = 0; j < 4; j++) bv[j] = Bs[tc*4+j][kk];
      #pragma unroll
      for (int i = 0; i < 4; i++)
        #pragma unroll
        for (int j = 0; j < 4; j++) acc[i][j] += a[i]*bv[j];
    }
    __syncthreads();
  }
  #pragma unroll
  for (int i = 0; i < 4; i++) {
    int gm = m0 + tr*4 + i;
    if (gm >= M) continue;
    #pragma unroll
    for (int j = 0; j < 4; j++) {
      int gn = n0 + tc*4 + j;
      if (gn < Nd) Cm[(size_t)gm*Nd + gn] = __float2bfloat16(acc[i][j]);
    }
  }
}

// ---------------------------------------------------------------------------
// Projection GEMM: C(fp32) = A(bf16) * B(fp32)^T + bias.
// ---------------------------------------------------------------------------
__global__ __launch_bounds__(256) void gemm_proj(const bf16* __restrict__ A,
    const float* __restrict__ Bm, const float* __restrict__ bias,
    float* __restrict__ Cm, int M, int Nd, int K)
{
  __shared__ float As[64][33];
  __shared__ float Bs[64][33];
  const int m0 = blockIdx.y * 64, n0 = blockIdx.x * 64;
  const int tid = threadIdx.x;
  const int tr = tid >> 4, tc = tid & 15;
  float acc[4][4] = {};
  for (int k0 = 0; k0 < K; k0 += 32) {
    // A tile: 64 rows x 32 bf16 = 4 chunks of 8 per row
    for (int i = tid; i < 64*4; i += 256) {
      int r = i >> 2, c8 = i & 3;
      int gr = m0 + r;
      if (gr < M) {
        us8 v = *(const us8*)&A[(size_t)gr*K + k0 + c8*8];
        #pragma unroll
        for (int j = 0; j < 8; j++) As[r][c8*8+j] = bf2f(v[j]);
      } else {
        #pragma unroll
        for (int j = 0; j < 8; j++) As[r][c8*8+j] = 0.f;
      }
    }
    for (int i = tid; i < 64*8; i += 256) {
      int r = i >> 3, cq = i & 7;
      int gr = n0 + r;
      float4 v = make_float4(0.f,0.f,0.f,0.f);
      if (gr < Nd) v = ld4(&Bm[(size_t)gr*K + k0 + cq*4]);
      Bs[r][cq*4+0]=v.x; Bs[r][cq*4+1]=v.y; Bs[r][cq*4+2]=v.z; Bs[r][cq*4+3]=v.w;
    }
    __syncthreads();
    #pragma unroll
    for (int kk = 0; kk < 32; kk++) {
      float a[4], bv[4];
      #pragma unroll
      for (int i = 0; i < 4; i++) a[i] = As[tr*4+i][kk];
      #pragma unroll
      for (int j = 0; j < 4; j++) bv[j] = Bs[tc*4+j][kk];
      #pragma unroll
      for (int i = 0; i < 4; i++)
        #pragma unroll
        for (int j = 0; j < 4; j++) acc[i][j] += a[i]*bv[j];
    }
    __syncthreads();
  }
  #pragma unroll
  for (int i = 0; i < 4; i++) {
    int gm = m0 + tr*4 + i;
    if (gm >= M) continue;
    #pragma unroll
    for (int j = 0; j < 4; j++) {
      int gn = n0 + tc*4 + j;
      if (gn < Nd) Cm[(size_t)gm*Nd + gn] = acc[i][j] + bias[gn];
    }
  }
}

// ---------------------------------------------------------------------------
// Channel attention: per site (b,h,n) a 13x13 softmax(QK^T) over hd=64.
// attn_c layout: [(b*H+h)*N + n][q(=13)][k(=13)]  (fp32)
// ---------------------------------------------------------------------------
__global__ __launch_bounds__(256) void chan_attn_k(const bf16* __restrict__ QKV,
                                                   float* __restrict__ attn_c)
{
  const int site = blockIdx.x;            // (b*H + h)*N + n
  const int n = site % NN; const int bh = site / NN;
  const int h = bh % HH;   const int b  = bh / HH;
  __shared__ float qs[CC*HD], ks[CC*HD], ls[CC*CC];
  const int tid = threadIdx.x;
  const size_t rowbase = (size_t)(b*NN + n) * CC;
  for (int i = tid; i < CC*HD; i += 256) {
    int c = i >> 6, d = i & 63;
    size_t idx = (rowbase + c)*E5 + h*HD + d;
    qs[i] = __bfloat162float(QKV[idx]);        // slice 0: qc
    ks[i] = __bfloat162float(QKV[idx + DD]);   // slice 1: kc
  }
  __syncthreads();
  if (tid < CC*CC) {
    int q = tid / CC, k = tid % CC;
    float s = 0.f;
    #pragma unroll
    for (int d = 0; d < HD; d++) s += qs[q*HD+d]*ks[k*HD+d];
    ls[tid] = s * 0.125f;
  }
  __syncthreads();
  if (tid < CC) {
    int q = tid;
    float m = -1e30f;
    #pragma unroll
    for (int k = 0; k < CC; k++) m = fmaxf(m, ls[q*CC+k]);
    float e[CC]; float sum = 0.f;
    #pragma unroll
    for (int k = 0; k < CC; k++) { e[k] = __expf(ls[q*CC+k]-m); sum += e[k]; }
    float inv = 1.f/sum;
    size_t base = (size_t)site*CC*CC + (size_t)q*CC;
    #pragma unroll
    for (int k = 0; k < CC; k++) attn_c[base+k] = e[k]*inv;
  }
}

// ---------------------------------------------------------------------------
// Spatial attention: per site (b,h,y): S = softmax_k( SCALE * Qs Ks^T ), 196x196.
// attn_s layout (bf16): [(b*H+h)*C + y][x(=196)][k(=196)]
// Block: 32 q-rows; thread t: q=t/8, owns k = (t%8)+8j.
// ---------------------------------------------------------------------------
__global__ __launch_bounds__(256) void spat_attn_k(const bf16* __restrict__ QKV,
                                                   bf16* __restrict__ attn_s)
{
  const int site = blockIdx.x;     // (b*H+h)*C + y
  const int y = site % CC; const int bh = site / CC;
  const int h = bh % HH;   const int b  = bh / HH;
  const int x0 = blockIdx.y * 32;
  __shared__ float Q[32][HD];
  __shared__ float Kt[64][HD];
  const int tid = threadIdx.x;
  // Q tile: 32 rows x 8 chunks of 8 bf16
  {
    int r = tid >> 3, c8 = tid & 7;
    int x = x0 + r;
    if (x < NN) {
      us8 v = *(const us8*)&QKV[((size_t)(b*NN + x)*CC + y)*E5 + 2*DD + h*HD + c8*8];
      #pragma unroll
      for (int j = 0; j < 8; j++) Q[r][c8*8+j] = bf2f(v[j]);
    } else {
      #pragma unroll
      for (int j = 0; j < 8; j++) Q[r][c8*8+j] = 0.f;
    }
  }
  const int q = tid >> 3, g = tid & 7;
  float acc[25];
  #pragma unroll
  for (int j = 0; j < 25; j++) acc[j] = 0.f;

  for (int k0 = 0; k0 < NN; k0 += 64) {
    __syncthreads();
    for (int i = tid; i < 64*8; i += 256) {
      int r = i >> 3, c8 = i & 7;
      int k = k0 + r;
      if (k < NN) {
        us8 v = *(const us8*)&QKV[((size_t)(b*NN + k)*CC + y)*E5 + 3*DD + h*HD + c8*8];
        #pragma unroll
        for (int j = 0; j < 8; j++) Kt[r][c8*8+j] = bf2f(v[j]);
      } else {
        #pragma unroll
        for (int j = 0; j < 8; j++) Kt[r][c8*8+j] = 0.f;
      }
    }
    __syncthreads();
    const int jlo = k0 >> 3;
    #pragma unroll
    for (int jj = 0; jj < 8; jj++) {
      int j = jlo + jj;
      if (j >= 25) break;
      int k = g + 8*j;
      if (k < NN) {
        int kk = k - k0;
        float s = 0.f;
        #pragma unroll
        for (int d4 = 0; d4 < 16; d4++) {
          float4 qv = ld4(&Q[q][d4*4]);
          float4 kv = ld4(&Kt[kk][d4*4]);
          s += qv.x*kv.x + qv.y*kv.y + qv.z*kv.z + qv.w*kv.w;
        }
        acc[j] = s * 0.125f;
      }
    }
  }
  // softmax across the 8-thread group owning a row
  float m = -1e30f;
  #pragma unroll
  for (int j = 0; j < 25; j++) { int k = g+8*j; if (k < NN) m = fmaxf(m, acc[j]); }
  #pragma unroll
  for (int s = 1; s < 8; s <<= 1) m = fmaxf(m, __shfl_xor(m, s));
  float e[25]; float sum = 0.f;
  #pragma unroll
  for (int j = 0; j < 25; j++) { int k = g+8*j; e[j] = 0.f; if (k < NN) { e[j] = __expf(acc[j]-m); sum += e[j]; } }
  #pragma unroll
  for (int s = 1; s < 8; s <<= 1) sum += __shfl_xor(sum, s);
  float inv = 1.f/sum;
  int x = x0 + q;
  if (x < NN) {
    size_t base = ((size_t)site*NN + x)*NN;
    #pragma unroll
    for (int j = 0; j < 25; j++) { int k = g+8*j; if (k < NN) attn_s[base+k] = __float2bfloat16(e[j]*inv); }
  }
}

// ---------------------------------------------------------------------------
// Fused PV + channel combine.
// out[x,y,d] = sum_c attn_c[b,h,x,y,c] * sum_n S_y[x,n] * v2[c,n,d]
// v2[c,n,:] = QKV[b*2548 + c*196 + n, 3072 + h*64 : +64]  (flat identity)
// Block: one (b,h,y) site x 64-row x-tile. Thread: 2 x-rows, 8 d.
// Writes bf16 outa in (B,N,C,D) layout with D = h*64+d.
// ---------------------------------------------------------------------------
__global__ __launch_bounds__(256) void pv_combine_k(const bf16* __restrict__ QKV,
    const bf16* __restrict__ attn_s, const float* __restrict__ attn_c,
    bf16* __restrict__ outa)
{
  const int site = blockIdx.x;     // (b*H+h)*C + y
  const int y = site % CC; const int bh = site / CC;
  const int h = bh % HH;   const int b  = bh / HH;
  const int x0 = blockIdx.y * 64;
  __shared__ float S[64][NN];      // 50.2 KB
  __shared__ float V2[32][HD];     // 8 KB
  __shared__ float AC[64][CC];     // 3.3 KB
  const int tid = threadIdx.x;
  for (int i = tid; i < 64*49; i += 256) {       // 49 chunks of 4 bf16 per row
    int r = i / 49, c4 = i % 49;
    int x = x0 + r;
    if (x < NN) {
      us4 v = *(const us4*)&attn_s[((size_t)site*NN + x)*NN + c4*4];
      #pragma unroll
      for (int j = 0; j < 4; j++) S[r][c4*4+j] = bf2f(v[j]);
    } else {
      #pragma unroll
      for (int j = 0; j < 4; j++) S[r][c4*4+j] = 0.f;
    }
  }
  for (int i = tid; i < 64*CC; i += 256) {
    int r = i / CC, c = i % CC;
    int x = x0 + r;
    AC[r][c] = (x < NN) ? attn_c[(((size_t)bh*NN + x)*CC + y)*CC + c] : 0.f;
  }
  const int xl = tid >> 3;            // 0..31 (also handles xl+32)
  const int d0 = (tid & 7) * 8;
  float o0[8], o1[8];
  #pragma unroll
  for (int j = 0; j < 8; j++) { o0[j] = 0.f; o1[j] = 0.f; }
  const size_t vrowbase = (size_t)b*NCH;
  for (int c = 0; c < CC; c++) {
    float t0[8], t1[8];
    #pragma unroll
    for (int j = 0; j < 8; j++) { t0[j] = 0.f; t1[j] = 0.f; }
    for (int n0 = 0; n0 < NN; n0 += 32) {
      const int nmax = (NN - n0 < 32) ? (NN - n0) : 32;
      __syncthreads();
      {
        int r = tid >> 3, c8 = tid & 7;     // 32 rows x 8 chunks of 8
        if (r < nmax) {
          us8 v = *(const us8*)&QKV[(vrowbase + (size_t)c*NN + n0 + r)*E5 + 4*DD + h*HD + c8*8];
          #pragma unroll
          for (int j = 0; j < 8; j++) V2[r][c8*8+j] = bf2f(v[j]);
        } else {
          #pragma unroll
          for (int j = 0; j < 8; j++) V2[r][c8*8+j] = 0.f;
        }
      }
      __syncthreads();
      for (int nn = 0; nn < nmax; nn++) {
        float s0 = S[xl][n0+nn];
        float s1 = S[xl+32][n0+nn];
        float4 v0 = ld4(&V2[nn][d0]);
        float4 v1 = ld4(&V2[nn][d0+4]);
        t0[0] += s0*v0.x; t0[1] += s0*v0.y; t0[2] += s0*v0.z; t0[3] += s0*v0.w;
        t0[4] += s0*v1.x; t0[5] += s0*v1.y; t0[6] += s0*v1.z; t0[7] += s0*v1.w;
        t1[0] += s1*v0.x; t1[1] += s1*v0.y; t1[2] += s1*v0.z; t1[3] += s1*v0.w;
        t1[4] += s1*v1.x; t1[5] += s1*v1.y; t1[6] += s1*v1.z; t1[7] += s1*v1.w;
      }
    }
    float a0 = AC[xl][c], a1 = AC[xl+32][c];
    #pragma unroll
    for (int j = 0; j < 8; j++) { o0[j] += a0*t0[j]; o1[j] += a1*t1[j]; }
  }
  int x = x0 + xl;
  if (x < NN) {
    size_t base = ((size_t)(b*NN + x)*CC + y)*DD + h*HD + d0;
    #pragma unroll
    for (int j = 0; j < 8; j++) outa[base+j] = __float2bfloat16(o0[j]);
  }
  x = x0 + xl + 32;
  if (x < NN) {
    size_t base = ((size_t)(b*NN + x)*CC + y)*DD + h*HD + d0;
    #pragma unroll
    for (int j = 0; j < 8; j++) outa[base+j] = __float2bfloat16(o1[j]);
  }
}

// ---------------------------------------------------------------------------
// Workspace (bytes): qkv bf16 78.3MB | attn_c fp32 6.4MB | attn_s bf16 48.0MB
// | outa bf16 15.7MB  => 148.2MB total (was 290MB fp32 -> suspected ws overflow)
// ---------------------------------------------------------------------------
extern "C" void kernel_launch(void* const* d_in, const int* in_sizes, int n_in,
                              void* d_out, int out_size, void* d_ws, size_t ws_size,
                              hipStream_t stream)
{
  const float* x     = (const float*)d_in[0];
  const float* Wqkv  = (const float*)d_in[1];
  const float* Wproj = (const float*)d_in[2];
  const float* bproj = (const float*)d_in[3];
  float* out = (float*)d_out;

  bf16*  qkv    = (bf16*)d_ws;                                    // RR*E5
  float* attn_c = (float*)(qkv + (size_t)RR*E5);                  // B*H*N*C*C
  bf16*  attn_s = (bf16*)(attn_c + (size_t)BB*HH*NN*CC*CC);       // B*H*C*N*N
  bf16*  outa   = attn_s + (size_t)BB*HH*CC*NN*NN;                // RR*DD

  // 1) QKV GEMM: (10192x768) x (3840x768)^T -> bf16
  gemm_qkv<<<dim3(E5/64, (RR+63)/64), 256, 0, stream>>>(x, Wqkv, qkv, RR, E5, DD);
  // 2) channel attention (13x13 per (b,h,n))
  chan_attn_k<<<dim3(BB*HH*NN), 256, 0, stream>>>(qkv, attn_c);
  // 3) spatial attention (196x196 per (b,h,y))
  spat_attn_k<<<dim3(BB*HH*CC, 7), 256, 0, stream>>>(qkv, attn_s);
  // 4) fused PV + channel combine -> (B,N,C,D) bf16
  pv_combine_k<<<dim3(BB*HH*CC, 4), 256, 0, stream>>>(qkv, attn_s, attn_c, outa);
  // 5) projection GEMM + bias -> fp32 out
  gemm_proj<<<dim3(DD/64, (RR+63)/64), 256, 0, stream>>>(outa, Wproj, bproj, out, RR, DD, DD);
}

// Round 4
// 2060.141 us; speedup vs baseline: 1.5746x; 1.5746x over previous
//
#include <hip/hip_runtime.h>
#include <hip/hip_bf16.h>

#define BB 4
#define NN 196
#define CC 13
#define DD 768
#define HH 12
#define HD 64
#define RR (BB*NN*CC)      /* 10192 */
#define E5 (5*DD)          /* 3840  */
#define NCH (NN*CC)        /* 2548  */

typedef __hip_bfloat16 bf16;
typedef __attribute__((ext_vector_type(8))) short bf16x8;   // MFMA A/B frag (4 VGPR)
typedef __attribute__((ext_vector_type(4))) float f32x4;    // MFMA C/D frag
typedef __attribute__((ext_vector_type(4))) unsigned short us4;
typedef __attribute__((ext_vector_type(8))) unsigned short us8;

static __device__ __forceinline__ float4 ld4(const float* p){ return *(const float4*)p; }
static __device__ __forceinline__ float bf2f(unsigned short u){ return __uint_as_float(((unsigned)u)<<16); }
static __device__ __forceinline__ unsigned short f2bf_bits(float f){
  __hip_bfloat16 h = __float2bfloat16(f);           // RNE
  return *(unsigned short*)&h;
}
static __device__ __forceinline__ us8 pack8(float4 f0, float4 f1){
  us8 w;
  w[0]=f2bf_bits(f0.x); w[1]=f2bf_bits(f0.y); w[2]=f2bf_bits(f0.z); w[3]=f2bf_bits(f0.w);
  w[4]=f2bf_bits(f1.x); w[5]=f2bf_bits(f1.y); w[6]=f2bf_bits(f1.z); w[7]=f2bf_bits(f1.w);
  return w;
}

// ---------------------------------------------------------------------------
// MFMA GEMM #1: C(bf16) = A(fp32) * B(fp32)^T.  A: MxK, B: NdxK row-major.
// BM=BN=128, BK=64, 256 thr = 4 waves, wave -> 64x64 subtile (4x4 frags of
// 16x16x32). fp32->bf16 conversion fused into LDS staging.
// LDS rows padded to 72 bf16 (144B): fragment ds_read_b128 at bank floor.
// N must be multiple of 128; K multiple of 64; M guarded.
// ---------------------------------------------------------------------------
__global__ __launch_bounds__(256) void gemm_qkv_mfma(const float* __restrict__ A,
    const float* __restrict__ Bm, bf16* __restrict__ Cm, int M, int Nd, int K)
{
  __shared__ short Als[128][72];
  __shared__ short Bls[128][72];
  const int m0 = blockIdx.y * 128, n0 = blockIdx.x * 128;
  const int tid = threadIdx.x;
  const int lane = tid & 63, wid = tid >> 6;
  const int wr = wid >> 1, wc = wid & 1;
  const int fr = lane & 15, hi = lane >> 4;
  const int Mrem = M - m0;
  f32x4 acc[4][4] = {};
  for (int k0 = 0; k0 < K; k0 += 64) {
    #pragma unroll
    for (int i = tid; i < 1024; i += 256) {     // A tile: 128 rows x 8 chunks
      int r = i >> 3, c8 = i & 7;
      us8 w = {0,0,0,0,0,0,0,0};
      if (r < Mrem) {
        const float* src = &A[(size_t)(m0 + r)*K + k0 + c8*8];
        w = pack8(ld4(src), ld4(src+4));
      }
      *(us8*)&Als[r][c8*8] = w;
    }
    #pragma unroll
    for (int i = tid; i < 1024; i += 256) {     // B tile (rows always valid)
      int r = i >> 3, c8 = i & 7;
      const float* src = &Bm[(size_t)(n0 + r)*K + k0 + c8*8];
      *(us8*)&Bls[r][c8*8] = pack8(ld4(src), ld4(src+4));
    }
    __syncthreads();
    #pragma unroll
    for (int kk = 0; kk < 64; kk += 32) {
      bf16x8 a[4], b[4];
      #pragma unroll
      for (int mi = 0; mi < 4; mi++) a[mi] = *(bf16x8*)&Als[wr*64 + mi*16 + fr][kk + hi*8];
      #pragma unroll
      for (int ni = 0; ni < 4; ni++) b[ni] = *(bf16x8*)&Bls[wc*64 + ni*16 + fr][kk + hi*8];
      #pragma unroll
      for (int mi = 0; mi < 4; mi++)
        #pragma unroll
        for (int ni = 0; ni < 4; ni++)
          acc[mi][ni] = __builtin_amdgcn_mfma_f32_16x16x32_bf16(a[mi], b[ni], acc[mi][ni], 0, 0, 0);
    }
    __syncthreads();
  }
  #pragma unroll
  for (int mi = 0; mi < 4; mi++) {
    #pragma unroll
    for (int j = 0; j < 4; j++) {
      int r = wr*64 + mi*16 + hi*4 + j;          // C/D: col=lane&15, row=hi*4+reg
      if (m0 + r < M) {
        #pragma unroll
        for (int ni = 0; ni < 4; ni++) {
          int cidx = n0 + wc*64 + ni*16 + fr;
          Cm[(size_t)(m0+r)*Nd + cidx] = __float2bfloat16(acc[mi][ni][j]);
        }
      }
    }
  }
}

// ---------------------------------------------------------------------------
// MFMA GEMM #2: C(fp32) = A(bf16) * B(fp32)^T + bias.  Same geometry.
// ---------------------------------------------------------------------------
__global__ __launch_bounds__(256) void gemm_proj_mfma(const bf16* __restrict__ A,
    const float* __restrict__ Bm, const float* __restrict__ bias,
    float* __restrict__ Cm, int M, int Nd, int K)
{
  __shared__ short Als[128][72];
  __shared__ short Bls[128][72];
  const int m0 = blockIdx.y * 128, n0 = blockIdx.x * 128;
  const int tid = threadIdx.x;
  const int lane = tid & 63, wid = tid >> 6;
  const int wr = wid >> 1, wc = wid & 1;
  const int fr = lane & 15, hi = lane >> 4;
  const int Mrem = M - m0;
  f32x4 acc[4][4] = {};
  for (int k0 = 0; k0 < K; k0 += 64) {
    #pragma unroll
    for (int i = tid; i < 1024; i += 256) {     // A tile: bf16 source, direct copy
      int r = i >> 3, c8 = i & 7;
      us8 w = {0,0,0,0,0,0,0,0};
      if (r < Mrem) w = *(const us8*)&A[(size_t)(m0 + r)*K + k0 + c8*8];
      *(us8*)&Als[r][c8*8] = w;
    }
    #pragma unroll
    for (int i = tid; i < 1024; i += 256) {
      int r = i >> 3, c8 = i & 7;
      const float* src = &Bm[(size_t)(n0 + r)*K + k0 + c8*8];
      *(us8*)&Bls[r][c8*8] = pack8(ld4(src), ld4(src+4));
    }
    __syncthreads();
    #pragma unroll
    for (int kk = 0; kk < 64; kk += 32) {
      bf16x8 a[4], b[4];
      #pragma unroll
      for (int mi = 0; mi < 4; mi++) a[mi] = *(bf16x8*)&Als[wr*64 + mi*16 + fr][kk + hi*8];
      #pragma unroll
      for (int ni = 0; ni < 4; ni++) b[ni] = *(bf16x8*)&Bls[wc*64 + ni*16 + fr][kk + hi*8];
      #pragma unroll
      for (int mi = 0; mi < 4; mi++)
        #pragma unroll
        for (int ni = 0; ni < 4; ni++)
          acc[mi][ni] = __builtin_amdgcn_mfma_f32_16x16x32_bf16(a[mi], b[ni], acc[mi][ni], 0, 0, 0);
    }
    __syncthreads();
  }
  #pragma unroll
  for (int mi = 0; mi < 4; mi++) {
    #pragma unroll
    for (int j = 0; j < 4; j++) {
      int r = wr*64 + mi*16 + hi*4 + j;
      if (m0 + r < M) {
        #pragma unroll
        for (int ni = 0; ni < 4; ni++) {
          int cidx = n0 + wc*64 + ni*16 + fr;
          Cm[(size_t)(m0+r)*Nd + cidx] = acc[mi][ni][j] + bias[cidx];
        }
      }
    }
  }
}

// ---------------------------------------------------------------------------
// Channel attention: per site (b,h,n) a 13x13 softmax(QK^T) over hd=64.
// attn_c layout: [(b*H+h)*N + n][q(=13)][k(=13)]  (fp32)
// ---------------------------------------------------------------------------
__global__ __launch_bounds__(256) void chan_attn_k(const bf16* __restrict__ QKV,
                                                   float* __restrict__ attn_c)
{
  const int site = blockIdx.x;            // (b*H + h)*N + n
  const int n = site % NN; const int bh = site / NN;
  const int h = bh % HH;   const int b  = bh / HH;
  __shared__ float qs[CC*HD], ks[CC*HD], ls[CC*CC];
  const int tid = threadIdx.x;
  const size_t rowbase = (size_t)(b*NN + n) * CC;
  for (int i = tid; i < CC*HD; i += 256) {
    int c = i >> 6, d = i & 63;
    size_t idx = (rowbase + c)*E5 + h*HD + d;
    qs[i] = __bfloat162float(QKV[idx]);        // slice 0: qc
    ks[i] = __bfloat162float(QKV[idx + DD]);   // slice 1: kc
  }
  __syncthreads();
  if (tid < CC*CC) {
    int q = tid / CC, k = tid % CC;
    float s = 0.f;
    #pragma unroll
    for (int d = 0; d < HD; d++) s += qs[q*HD+d]*ks[k*HD+d];
    ls[tid] = s * 0.125f;
  }
  __syncthreads();
  if (tid < CC) {
    int q = tid;
    float m = -1e30f;
    #pragma unroll
    for (int k = 0; k < CC; k++) m = fmaxf(m, ls[q*CC+k]);
    float e[CC]; float sum = 0.f;
    #pragma unroll
    for (int k = 0; k < CC; k++) { e[k] = __expf(ls[q*CC+k]-m); sum += e[k]; }
    float inv = 1.f/sum;
    size_t base = (size_t)site*CC*CC + (size_t)q*CC;
    #pragma unroll
    for (int k = 0; k < CC; k++) attn_c[base+k] = e[k]*inv;
  }
}

// ---------------------------------------------------------------------------
// Spatial attention: per site (b,h,y): S = softmax_k( SCALE * Qs Ks^T ), 196x196.
// attn_s layout (bf16): [(b*H+h)*C + y][x(=196)][k(=196)]
// ---------------------------------------------------------------------------
__global__ __launch_bounds__(256) void spat_attn_k(const bf16* __restrict__ QKV,
                                                   bf16* __restrict__ attn_s)
{
  const int site = blockIdx.x;     // (b*H+h)*C + y
  const int y = site % CC; const int bh = site / CC;
  const int h = bh % HH;   const int b  = bh / HH;
  const int x0 = blockIdx.y * 32;
  __shared__ float Q[32][HD];
  __shared__ float Kt[64][HD];
  const int tid = threadIdx.x;
  {
    int r = tid >> 3, c8 = tid & 7;
    int x = x0 + r;
    if (x < NN) {
      us8 v = *(const us8*)&QKV[((size_t)(b*NN + x)*CC + y)*E5 + 2*DD + h*HD + c8*8];
      #pragma unroll
      for (int j = 0; j < 8; j++) Q[r][c8*8+j] = bf2f(v[j]);
    } else {
      #pragma unroll
      for (int j = 0; j < 8; j++) Q[r][c8*8+j] = 0.f;
    }
  }
  const int q = tid >> 3, g = tid & 7;
  float acc[25];
  #pragma unroll
  for (int j = 0; j < 25; j++) acc[j] = 0.f;

  for (int k0 = 0; k0 < NN; k0 += 64) {
    __syncthreads();
    for (int i = tid; i < 64*8; i += 256) {
      int r = i >> 3, c8 = i & 7;
      int k = k0 + r;
      if (k < NN) {
        us8 v = *(const us8*)&QKV[((size_t)(b*NN + k)*CC + y)*E5 + 3*DD + h*HD + c8*8];
        #pragma unroll
        for (int j = 0; j < 8; j++) Kt[r][c8*8+j] = bf2f(v[j]);
      } else {
        #pragma unroll
        for (int j = 0; j < 8; j++) Kt[r][c8*8+j] = 0.f;
      }
    }
    __syncthreads();
    const int jlo = k0 >> 3;
    #pragma unroll
    for (int jj = 0; jj < 8; jj++) {
      int j = jlo + jj;
      if (j >= 25) break;
      int k = g + 8*j;
      if (k < NN) {
        int kk = k - k0;
        float s = 0.f;
        #pragma unroll
        for (int d4 = 0; d4 < 16; d4++) {
          float4 qv = ld4(&Q[q][d4*4]);
          float4 kv = ld4(&Kt[kk][d4*4]);
          s += qv.x*kv.x + qv.y*kv.y + qv.z*kv.z + qv.w*kv.w;
        }
        acc[j] = s * 0.125f;
      }
    }
  }
  float m = -1e30f;
  #pragma unroll
  for (int j = 0; j < 25; j++) { int k = g+8*j; if (k < NN) m = fmaxf(m, acc[j]); }
  #pragma unroll
  for (int s = 1; s < 8; s <<= 1) m = fmaxf(m, __shfl_xor(m, s));
  float e[25]; float sum = 0.f;
  #pragma unroll
  for (int j = 0; j < 25; j++) { int k = g+8*j; e[j] = 0.f; if (k < NN) { e[j] = __expf(acc[j]-m); sum += e[j]; } }
  #pragma unroll
  for (int s = 1; s < 8; s <<= 1) sum += __shfl_xor(sum, s);
  float inv = 1.f/sum;
  int x = x0 + q;
  if (x < NN) {
    size_t base = ((size_t)site*NN + x)*NN;
    #pragma unroll
    for (int j = 0; j < 25; j++) { int k = g+8*j; if (k < NN) attn_s[base+k] = __float2bfloat16(e[j]*inv); }
  }
}

// ---------------------------------------------------------------------------
// Fused PV + channel combine (unchanged from passing round 3).
// out[x,y,d] = sum_c attn_c[b,h,x,y,c] * sum_n S_y[x,n] * v2[c,n,d]
// v2[c,n,:] = QKV[b*2548 + c*196 + n, 3072 + h*64 : +64]  (flat identity)
// ---------------------------------------------------------------------------
__global__ __launch_bounds__(256) void pv_combine_k(const bf16* __restrict__ QKV,
    const bf16* __restrict__ attn_s, const float* __restrict__ attn_c,
    bf16* __restrict__ outa)
{
  const int site = blockIdx.x;     // (b*H+h)*C + y
  const int y = site % CC; const int bh = site / CC;
  const int h = bh % HH;   const int b  = bh / HH;
  const int x0 = blockIdx.y * 64;
  __shared__ float S[64][NN];      // 50.2 KB
  __shared__ float V2[32][HD];     // 8 KB
  __shared__ float AC[64][CC];     // 3.3 KB
  const int tid = threadIdx.x;
  for (int i = tid; i < 64*49; i += 256) {
    int r = i / 49, c4 = i % 49;
    int x = x0 + r;
    if (x < NN) {
      us4 v = *(const us4*)&attn_s[((size_t)site*NN + x)*NN + c4*4];
      #pragma unroll
      for (int j = 0; j < 4; j++) S[r][c4*4+j] = bf2f(v[j]);
    } else {
      #pragma unroll
      for (int j = 0; j < 4; j++) S[r][c4*4+j] = 0.f;
    }
  }
  for (int i = tid; i < 64*CC; i += 256) {
    int r = i / CC, c = i % CC;
    int x = x0 + r;
    AC[r][c] = (x < NN) ? attn_c[(((size_t)bh*NN + x)*CC + y)*CC + c] : 0.f;
  }
  const int xl = tid >> 3;
  const int d0 = (tid & 7) * 8;
  float o0[8], o1[8];
  #pragma unroll
  for (int j = 0; j < 8; j++) { o0[j] = 0.f; o1[j] = 0.f; }
  const size_t vrowbase = (size_t)b*NCH;
  for (int c = 0; c < CC; c++) {
    float t0[8], t1[8];
    #pragma unroll
    for (int j = 0; j < 8; j++) { t0[j] = 0.f; t1[j] = 0.f; }
    for (int n0 = 0; n0 < NN; n0 += 32) {
      const int nmax = (NN - n0 < 32) ? (NN - n0) : 32;
      __syncthreads();
      {
        int r = tid >> 3, c8 = tid & 7;
        if (r < nmax) {
          us8 v = *(const us8*)&QKV[(vrowbase + (size_t)c*NN + n0 + r)*E5 + 4*DD + h*HD + c8*8];
          #pragma unroll
          for (int j = 0; j < 8; j++) V2[r][c8*8+j] = bf2f(v[j]);
        } else {
          #pragma unroll
          for (int j = 0; j < 8; j++) V2[r][c8*8+j] = 0.f;
        }
      }
      __syncthreads();
      for (int nn = 0; nn < nmax; nn++) {
        float s0 = S[xl][n0+nn];
        float s1 = S[xl+32][n0+nn];
        float4 v0 = ld4(&V2[nn][d0]);
        float4 v1 = ld4(&V2[nn][d0+4]);
        t0[0] += s0*v0.x; t0[1] += s0*v0.y; t0[2] += s0*v0.z; t0[3] += s0*v0.w;
        t0[4] += s0*v1.x; t0[5] += s0*v1.y; t0[6] += s0*v1.z; t0[7] += s0*v1.w;
        t1[0] += s1*v0.x; t1[1] += s1*v0.y; t1[2] += s1*v0.z; t1[3] += s1*v0.w;
        t1[4] += s1*v1.x; t1[5] += s1*v1.y; t1[6] += s1*v1.z; t1[7] += s1*v1.w;
      }
    }
    float a0 = AC[xl][c], a1 = AC[xl+32][c];
    #pragma unroll
    for (int j = 0; j < 8; j++) { o0[j] += a0*t0[j]; o1[j] += a1*t1[j]; }
  }
  int x = x0 + xl;
  if (x < NN) {
    size_t base = ((size_t)(b*NN + x)*CC + y)*DD + h*HD + d0;
    #pragma unroll
    for (int j = 0; j < 8; j++) outa[base+j] = __float2bfloat16(o0[j]);
  }
  x = x0 + xl + 32;
  if (x < NN) {
    size_t base = ((size_t)(b*NN + x)*CC + y)*DD + h*HD + d0;
    #pragma unroll
    for (int j = 0; j < 8; j++) outa[base+j] = __float2bfloat16(o1[j]);
  }
}

// ---------------------------------------------------------------------------
// Workspace: qkv bf16 78.3MB | attn_c fp32 6.4MB | attn_s bf16 48.0MB
// | outa bf16 15.7MB => 148.2MB (known-good from round 3).
// ---------------------------------------------------------------------------
extern "C" void kernel_launch(void* const* d_in, const int* in_sizes, int n_in,
                              void* d_out, int out_size, void* d_ws, size_t ws_size,
                              hipStream_t stream)
{
  const float* x     = (const float*)d_in[0];
  const float* Wqkv  = (const float*)d_in[1];
  const float* Wproj = (const float*)d_in[2];
  const float* bproj = (const float*)d_in[3];
  float* out = (float*)d_out;

  bf16*  qkv    = (bf16*)d_ws;                                    // RR*E5
  float* attn_c = (float*)(qkv + (size_t)RR*E5);                  // B*H*N*C*C
  bf16*  attn_s = (bf16*)(attn_c + (size_t)BB*HH*NN*CC*CC);       // B*H*C*N*N
  bf16*  outa   = attn_s + (size_t)BB*HH*CC*NN*NN;                // RR*DD

  // 1) QKV GEMM (MFMA): (10192x768) x (3840x768)^T -> bf16
  gemm_qkv_mfma<<<dim3(E5/128, (RR+127)/128), 256, 0, stream>>>(x, Wqkv, qkv, RR, E5, DD);
  // 2) channel attention (13x13 per (b,h,n))
  chan_attn_k<<<dim3(BB*HH*NN), 256, 0, stream>>>(qkv, attn_c);
  // 3) spatial attention (196x196 per (b,h,y))
  spat_attn_k<<<dim3(BB*HH*CC, 7), 256, 0, stream>>>(qkv, attn_s);
  // 4) fused PV + channel combine -> (B,N,C,D) bf16
  pv_combine_k<<<dim3(BB*HH*CC, 4), 256, 0, stream>>>(qkv, attn_s, attn_c, outa);
  // 5) projection GEMM (MFMA) + bias -> fp32 out
  gemm_proj_mfma<<<dim3(DD/128, (RR+127)/128), 256, 0, stream>>>(outa, Wproj, bproj, out, RR, DD, DD);
}

// Round 6
// 1209.663 us; speedup vs baseline: 2.6816x; 1.7031x over previous
//
#include <hip/hip_runtime.h>
#include <hip/hip_bf16.h>

#define BB 4
#define NN 196
#define CC 13
#define DD 768
#define HH 12
#define HD 64
#define RR (BB*NN*CC)      /* 10192 */
#define E5 (5*DD)          /* 3840  */
#define NCH (NN*CC)        /* 2548  */
#define KP 224             /* padded spatial-K (196 -> 224, 7x32) */

typedef __hip_bfloat16 bf16;
typedef __attribute__((ext_vector_type(8))) short bf16x8;   // MFMA A/B frag (4 VGPR)
typedef __attribute__((ext_vector_type(4))) float f32x4;    // MFMA C/D frag
typedef __attribute__((ext_vector_type(4))) unsigned short us4;
typedef __attribute__((ext_vector_type(8))) unsigned short us8;

static __device__ __forceinline__ float4 ld4(const float* p){ return *(const float4*)p; }
static __device__ __forceinline__ float bf2f(unsigned short u){ return __uint_as_float(((unsigned)u)<<16); }
static __device__ __forceinline__ unsigned short f2bf_bits(float f){
  __hip_bfloat16 h = __float2bfloat16(f);           // RNE
  return *(unsigned short*)&h;
}
static __device__ __forceinline__ us8 pack8(float4 f0, float4 f1){
  us8 w;
  w[0]=f2bf_bits(f0.x); w[1]=f2bf_bits(f0.y); w[2]=f2bf_bits(f0.z); w[3]=f2bf_bits(f0.w);
  w[4]=f2bf_bits(f1.x); w[5]=f2bf_bits(f1.y); w[6]=f2bf_bits(f1.z); w[7]=f2bf_bits(f1.w);
  return w;
}

// ---------------------------------------------------------------------------
// MFMA GEMM #1: C(bf16) = A(fp32) * B(fp32)^T.  (unchanged, passing)
// ---------------------------------------------------------------------------
__global__ __launch_bounds__(256) void gemm_qkv_mfma(const float* __restrict__ A,
    const float* __restrict__ Bm, bf16* __restrict__ Cm, int M, int Nd, int K)
{
  __shared__ short Als[128][72];
  __shared__ short Bls[128][72];
  const int m0 = blockIdx.y * 128, n0 = blockIdx.x * 128;
  const int tid = threadIdx.x;
  const int lane = tid & 63, wid = tid >> 6;
  const int wr = wid >> 1, wc = wid & 1;
  const int fr = lane & 15, hi = lane >> 4;
  const int Mrem = M - m0;
  f32x4 acc[4][4] = {};
  for (int k0 = 0; k0 < K; k0 += 64) {
    #pragma unroll
    for (int i = tid; i < 1024; i += 256) {
      int r = i >> 3, c8 = i & 7;
      us8 w = {0,0,0,0,0,0,0,0};
      if (r < Mrem) {
        const float* src = &A[(size_t)(m0 + r)*K + k0 + c8*8];
        w = pack8(ld4(src), ld4(src+4));
      }
      *(us8*)&Als[r][c8*8] = w;
    }
    #pragma unroll
    for (int i = tid; i < 1024; i += 256) {
      int r = i >> 3, c8 = i & 7;
      const float* src = &Bm[(size_t)(n0 + r)*K + k0 + c8*8];
      *(us8*)&Bls[r][c8*8] = pack8(ld4(src), ld4(src+4));
    }
    __syncthreads();
    #pragma unroll
    for (int kk = 0; kk < 64; kk += 32) {
      bf16x8 a[4], b[4];
      #pragma unroll
      for (int mi = 0; mi < 4; mi++) a[mi] = *(bf16x8*)&Als[wr*64 + mi*16 + fr][kk + hi*8];
      #pragma unroll
      for (int ni = 0; ni < 4; ni++) b[ni] = *(bf16x8*)&Bls[wc*64 + ni*16 + fr][kk + hi*8];
      #pragma unroll
      for (int mi = 0; mi < 4; mi++)
        #pragma unroll
        for (int ni = 0; ni < 4; ni++)
          acc[mi][ni] = __builtin_amdgcn_mfma_f32_16x16x32_bf16(a[mi], b[ni], acc[mi][ni], 0, 0, 0);
    }
    __syncthreads();
  }
  #pragma unroll
  for (int mi = 0; mi < 4; mi++) {
    #pragma unroll
    for (int j = 0; j < 4; j++) {
      int r = wr*64 + mi*16 + hi*4 + j;
      if (m0 + r < M) {
        #pragma unroll
        for (int ni = 0; ni < 4; ni++) {
          int cidx = n0 + wc*64 + ni*16 + fr;
          Cm[(size_t)(m0+r)*Nd + cidx] = __float2bfloat16(acc[mi][ni][j]);
        }
      }
    }
  }
}

// ---------------------------------------------------------------------------
// MFMA GEMM #2: C(fp32) = A(bf16) * B(fp32)^T + bias.  (unchanged, passing)
// ---------------------------------------------------------------------------
__global__ __launch_bounds__(256) void gemm_proj_mfma(const bf16* __restrict__ A,
    const float* __restrict__ Bm, const float* __restrict__ bias,
    float* __restrict__ Cm, int M, int Nd, int K)
{
  __shared__ short Als[128][72];
  __shared__ short Bls[128][72];
  const int m0 = blockIdx.y * 128, n0 = blockIdx.x * 128;
  const int tid = threadIdx.x;
  const int lane = tid & 63, wid = tid >> 6;
  const int wr = wid >> 1, wc = wid & 1;
  const int fr = lane & 15, hi = lane >> 4;
  const int Mrem = M - m0;
  f32x4 acc[4][4] = {};
  for (int k0 = 0; k0 < K; k0 += 64) {
    #pragma unroll
    for (int i = tid; i < 1024; i += 256) {
      int r = i >> 3, c8 = i & 7;
      us8 w = {0,0,0,0,0,0,0,0};
      if (r < Mrem) w = *(const us8*)&A[(size_t)(m0 + r)*K + k0 + c8*8];
      *(us8*)&Als[r][c8*8] = w;
    }
    #pragma unroll
    for (int i = tid; i < 1024; i += 256) {
      int r = i >> 3, c8 = i & 7;
      const float* src = &Bm[(size_t)(n0 + r)*K + k0 + c8*8];
      *(us8*)&Bls[r][c8*8] = pack8(ld4(src), ld4(src+4));
    }
    __syncthreads();
    #pragma unroll
    for (int kk = 0; kk < 64; kk += 32) {
      bf16x8 a[4], b[4];
      #pragma unroll
      for (int mi = 0; mi < 4; mi++) a[mi] = *(bf16x8*)&Als[wr*64 + mi*16 + fr][kk + hi*8];
      #pragma unroll
      for (int ni = 0; ni < 4; ni++) b[ni] = *(bf16x8*)&Bls[wc*64 + ni*16 + fr][kk + hi*8];
      #pragma unroll
      for (int mi = 0; mi < 4; mi++)
        #pragma unroll
        for (int ni = 0; ni < 4; ni++)
          acc[mi][ni] = __builtin_amdgcn_mfma_f32_16x16x32_bf16(a[mi], b[ni], acc[mi][ni], 0, 0, 0);
    }
    __syncthreads();
  }
  #pragma unroll
  for (int mi = 0; mi < 4; mi++) {
    #pragma unroll
    for (int j = 0; j < 4; j++) {
      int r = wr*64 + mi*16 + hi*4 + j;
      if (m0 + r < M) {
        #pragma unroll
        for (int ni = 0; ni < 4; ni++) {
          int cidx = n0 + wc*64 + ni*16 + fr;
          Cm[(size_t)(m0+r)*Nd + cidx] = acc[mi][ni][j] + bias[cidx];
        }
      }
    }
  }
}

// ---------------------------------------------------------------------------
// Channel attention (unchanged, passing).
// ---------------------------------------------------------------------------
__global__ __launch_bounds__(256) void chan_attn_k(const bf16* __restrict__ QKV,
                                                   float* __restrict__ attn_c)
{
  const int site = blockIdx.x;            // (b*H + h)*N + n
  const int n = site % NN; const int bh = site / NN;
  const int h = bh % HH;   const int b  = bh / HH;
  __shared__ float qs[CC*HD], ks[CC*HD], ls[CC*CC];
  const int tid = threadIdx.x;
  const size_t rowbase = (size_t)(b*NN + n) * CC;
  for (int i = tid; i < CC*HD; i += 256) {
    int c = i >> 6, d = i & 63;
    size_t idx = (rowbase + c)*E5 + h*HD + d;
    qs[i] = __bfloat162float(QKV[idx]);
    ks[i] = __bfloat162float(QKV[idx + DD]);
  }
  __syncthreads();
  if (tid < CC*CC) {
    int q = tid / CC, k = tid % CC;
    float s = 0.f;
    #pragma unroll
    for (int d = 0; d < HD; d++) s += qs[q*HD+d]*ks[k*HD+d];
    ls[tid] = s * 0.125f;
  }
  __syncthreads();
  if (tid < CC) {
    int q = tid;
    float m = -1e30f;
    #pragma unroll
    for (int k = 0; k < CC; k++) m = fmaxf(m, ls[q*CC+k]);
    float e[CC]; float sum = 0.f;
    #pragma unroll
    for (int k = 0; k < CC; k++) { e[k] = __expf(ls[q*CC+k]-m); sum += e[k]; }
    float inv = 1.f/sum;
    size_t base = (size_t)site*CC*CC + (size_t)q*CC;
    #pragma unroll
    for (int k = 0; k < CC; k++) attn_c[base+k] = e[k]*inv;
  }
}

// ---------------------------------------------------------------------------
// Spatial attention -> attn_s rows padded to KP=224 (zeros for k>=196) so the
// PV MFMA can K-loop in clean 32-steps with 16B-aligned us8/b128 accesses.
// ---------------------------------------------------------------------------
__global__ __launch_bounds__(256) void spat_attn_k(const bf16* __restrict__ QKV,
                                                   bf16* __restrict__ attn_s)
{
  const int site = blockIdx.x;     // (b*H+h)*C + y
  const int y = site % CC; const int bh = site / CC;
  const int h = bh % HH;   const int b  = bh / HH;
  const int x0 = blockIdx.y * 32;
  __shared__ float Q[32][HD];
  __shared__ float Kt[64][HD];
  const int tid = threadIdx.x;
  {
    int r = tid >> 3, c8 = tid & 7;
    int x = x0 + r;
    if (x < NN) {
      us8 v = *(const us8*)&QKV[((size_t)(b*NN + x)*CC + y)*E5 + 2*DD + h*HD + c8*8];
      #pragma unroll
      for (int j = 0; j < 8; j++) Q[r][c8*8+j] = bf2f(v[j]);
    } else {
      #pragma unroll
      for (int j = 0; j < 8; j++) Q[r][c8*8+j] = 0.f;
    }
  }
  const int q = tid >> 3, g = tid & 7;
  float acc[25];
  #pragma unroll
  for (int j = 0; j < 25; j++) acc[j] = 0.f;

  for (int k0 = 0; k0 < NN; k0 += 64) {
    __syncthreads();
    for (int i = tid; i < 64*8; i += 256) {
      int r = i >> 3, c8 = i & 7;
      int k = k0 + r;
      if (k < NN) {
        us8 v = *(const us8*)&QKV[((size_t)(b*NN + k)*CC + y)*E5 + 3*DD + h*HD + c8*8];
        #pragma unroll
        for (int j = 0; j < 8; j++) Kt[r][c8*8+j] = bf2f(v[j]);
      } else {
        #pragma unroll
        for (int j = 0; j < 8; j++) Kt[r][c8*8+j] = 0.f;
      }
    }
    __syncthreads();
    const int jlo = k0 >> 3;
    #pragma unroll
    for (int jj = 0; jj < 8; jj++) {
      int j = jlo + jj;
      if (j >= 25) break;
      int k = g + 8*j;
      if (k < NN) {
        int kk = k - k0;
        float s = 0.f;
        #pragma unroll
        for (int d4 = 0; d4 < 16; d4++) {
          float4 qv = ld4(&Q[q][d4*4]);
          float4 kv = ld4(&Kt[kk][d4*4]);
          s += qv.x*kv.x + qv.y*kv.y + qv.z*kv.z + qv.w*kv.w;
        }
        acc[j] = s * 0.125f;
      }
    }
  }
  float m = -1e30f;
  #pragma unroll
  for (int j = 0; j < 25; j++) { int k = g+8*j; if (k < NN) m = fmaxf(m, acc[j]); }
  #pragma unroll
  for (int s = 1; s < 8; s <<= 1) m = fmaxf(m, __shfl_xor(m, s));
  float e[25]; float sum = 0.f;
  #pragma unroll
  for (int j = 0; j < 25; j++) { int k = g+8*j; e[j] = 0.f; if (k < NN) { e[j] = __expf(acc[j]-m); sum += e[j]; } }
  #pragma unroll
  for (int s = 1; s < 8; s <<= 1) sum += __shfl_xor(sum, s);
  float inv = 1.f/sum;
  int x = x0 + q;
  if (x < NN) {
    size_t base = ((size_t)site*NN + x)*KP;
    #pragma unroll
    for (int j = 0; j < 28; j++) {           // cover full padded row 0..223
      int k = g + 8*j;
      attn_s[base+k] = (k < NN && j < 25) ? __float2bfloat16(e[j]*inv) : __float2bfloat16(0.f);
    }
  }
}

// ---------------------------------------------------------------------------
// V transpose: Vt[(b*H+h)*C + c][d(=64)][n(=224, zero-padded)] bf16, where
// source v2[c,n,d] = QKV[b*2548 + c*196 + n][3072 + h*64 + d].
// ---------------------------------------------------------------------------
__global__ __launch_bounds__(256) void v_transpose_k(const bf16* __restrict__ QKV,
                                                     bf16* __restrict__ Vt)
{
  const int bhc = blockIdx.x;         // ((b*H+h)*C + c)
  const int c = bhc % CC; const int bh = bhc / CC;
  const int h = bh % HH;  const int b  = bh / HH;
  __shared__ short T[196][72];        // [n][d], padded stride
  const int tid = threadIdx.x;
  for (int i = tid; i < 196*8; i += 256) {
    int n = i >> 3, c8 = i & 7;
    us8 v = *(const us8*)&QKV[((size_t)b*NCH + c*NN + n)*E5 + 4*DD + h*HD + c8*8];
    *(us8*)&T[n][c8*8] = v;
  }
  __syncthreads();
  const size_t obase = (size_t)bhc * HD * KP;
  for (int i = tid; i < 64*28; i += 256) {
    int d = i / 28, n8 = i % 28;
    us8 w;
    #pragma unroll
    for (int j = 0; j < 8; j++) {
      int n = n8*8 + j;
      w[j] = (n < NN) ? (unsigned short)T[n][d] : (unsigned short)0;
    }
    *(us8*)&Vt[obase + (size_t)d*KP + n8*8] = w;
  }
}

// ---------------------------------------------------------------------------
// PV + channel combine, MFMA version.
// Per block: site (b,h,y), 64-row x-tile. 4 waves; wave w owns rows
// [x0+16w, x0+16w+16), 4 n-frags (d=0..63). S staged once; per c: stage
// Vt tile, GEMM-accumulate T_c over K=224 (zero-padded), then
// out += AC[x,c]*T_c in fp32.
// ---------------------------------------------------------------------------
__global__ __launch_bounds__(256) void pv_mfma_k(const bf16* __restrict__ Vt,
    const bf16* __restrict__ attn_s, const float* __restrict__ attn_c,
    bf16* __restrict__ outa)
{
  const int site = blockIdx.x;     // (b*H+h)*C + y
  const int y = site % CC; const int bh = site / CC;
  const int h = bh % HH;   const int b  = bh / HH;
  const int x0 = blockIdx.y * 64;
  __shared__ short Sls[64][232];   // row 464B: 16B-aligned, ~4-way banks on b128
  __shared__ short Vls[64][232];
  __shared__ float AC[64][CC];
  const int tid = threadIdx.x;
  const int lane = tid & 63, w = tid >> 6;
  const int fr = lane & 15, hi = lane >> 4;

  // stage S rows (once) and AC
  for (int i = tid; i < 64*28; i += 256) {
    int r = i / 28, k8 = i % 28;
    int x = x0 + r;
    us8 v = {0,0,0,0,0,0,0,0};
    if (x < NN) v = *(const us8*)&attn_s[((size_t)site*NN + x)*KP + k8*8];
    *(us8*)&Sls[r][k8*8] = v;
  }
  for (int i = tid; i < 64*CC; i += 256) {
    int r = i / CC, c = i % CC;
    int x = x0 + r;
    AC[r][c] = (x < NN) ? attn_c[(((size_t)bh*NN + x)*CC + y)*CC + c] : 0.f;
  }

  f32x4 oacc[4] = {};
  for (int c = 0; c < CC; c++) {
    __syncthreads();                       // prev-c MFMA reads done (also covers S/AC on c=0)
    const size_t vbase = (size_t)(bh*CC + c) * HD * KP;
    for (int i = tid; i < 64*28; i += 256) {
      int d = i / 28, k8 = i % 28;
      *(us8*)&Vls[d][k8*8] = *(const us8*)&Vt[vbase + (size_t)d*KP + k8*8];
    }
    __syncthreads();
    f32x4 tacc[4] = {};
    #pragma unroll
    for (int kk = 0; kk < KP; kk += 32) {
      bf16x8 a = *(bf16x8*)&Sls[w*16 + fr][kk + hi*8];
      #pragma unroll
      for (int ni = 0; ni < 4; ni++) {
        bf16x8 bv = *(bf16x8*)&Vls[ni*16 + fr][kk + hi*8];
        tacc[ni] = __builtin_amdgcn_mfma_f32_16x16x32_bf16(a, bv, tacc[ni], 0, 0, 0);
      }
    }
    #pragma unroll
    for (int j = 0; j < 4; j++) {
      float ac = AC[w*16 + hi*4 + j][c];   // broadcast across fr lanes
      #pragma unroll
      for (int ni = 0; ni < 4; ni++) oacc[ni][j] += ac * tacc[ni][j];
    }
  }
  // epilogue: rows x = x0 + w*16 + hi*4 + j, cols d = ni*16 + fr
  #pragma unroll
  for (int j = 0; j < 4; j++) {
    int x = x0 + w*16 + hi*4 + j;
    if (x < NN) {
      size_t base = ((size_t)(b*NN + x)*CC + y)*DD + h*HD;
      #pragma unroll
      for (int ni = 0; ni < 4; ni++)
        outa[base + ni*16 + fr] = __float2bfloat16(oacc[ni][j]);
    }
  }
}

// ---------------------------------------------------------------------------
// Workspace: qkv bf16 78.3MB | attn_c f32 6.4MB | attn_s bf16(224) 54.8MB
// | Vt bf16 17.9MB | outa bf16 15.7MB  => ~173MB
// ---------------------------------------------------------------------------
extern "C" void kernel_launch(void* const* d_in, const int* in_sizes, int n_in,
                              void* d_out, int out_size, void* d_ws, size_t ws_size,
                              hipStream_t stream)
{
  const float* x     = (const float*)d_in[0];
  const float* Wqkv  = (const float*)d_in[1];
  const float* Wproj = (const float*)d_in[2];
  const float* bproj = (const float*)d_in[3];
  float* out = (float*)d_out;

  bf16*  qkv    = (bf16*)d_ws;                                    // RR*E5
  float* attn_c = (float*)(qkv + (size_t)RR*E5);                  // B*H*N*C*C
  bf16*  attn_s = (bf16*)(attn_c + (size_t)BB*HH*NN*CC*CC);       // 624*196*KP
  bf16*  Vt     = attn_s + (size_t)BB*HH*CC*NN*KP;                // 624*64*KP
  bf16*  outa   = Vt     + (size_t)BB*HH*CC*HD*KP;                // RR*DD

  // 1) QKV GEMM (MFMA)
  gemm_qkv_mfma<<<dim3(E5/128, (RR+127)/128), 256, 0, stream>>>(x, Wqkv, qkv, RR, E5, DD);
  // 2) channel attention
  chan_attn_k<<<dim3(BB*HH*NN), 256, 0, stream>>>(qkv, attn_c);
  // 3) spatial attention (padded-row output)
  spat_attn_k<<<dim3(BB*HH*CC, 7), 256, 0, stream>>>(qkv, attn_s);
  // 4) V transpose for MFMA B-operand
  v_transpose_k<<<dim3(BB*HH*CC), 256, 0, stream>>>(qkv, Vt);
  // 5) PV + combine (MFMA)
  pv_mfma_k<<<dim3(BB*HH*CC, 4), 256, 0, stream>>>(Vt, attn_s, attn_c, outa);
  // 6) projection GEMM (MFMA) + bias
  gemm_proj_mfma<<<dim3(DD/128, (RR+127)/128), 256, 0, stream>>>(outa, Wproj, bproj, out, RR, DD, DD);
}

// Round 7
// 654.124 us; speedup vs baseline: 4.9590x; 1.8493x over previous
//
#include <hip/hip_runtime.h>
#include <hip/hip_bf16.h>

#define BB 4
#define NN 196
#define CC 13
#define DD 768
#define HH 12
#define HD 64
#define RR (BB*NN*CC)      /* 10192 */
#define E5 (5*DD)          /* 3840  */
#define NCH (NN*CC)        /* 2548  */
#define KP 224             /* padded spatial-K (196 -> 224, 7x32) */

typedef __hip_bfloat16 bf16;
typedef __attribute__((ext_vector_type(8))) short bf16x8;   // MFMA A/B frag (4 VGPR)
typedef __attribute__((ext_vector_type(4))) float f32x4;    // MFMA C/D frag
typedef __attribute__((ext_vector_type(4))) unsigned short us4;
typedef __attribute__((ext_vector_type(8))) unsigned short us8;

static __device__ __forceinline__ float4 ld4(const float* p){ return *(const float4*)p; }
static __device__ __forceinline__ float bf2f(unsigned short u){ return __uint_as_float(((unsigned)u)<<16); }
static __device__ __forceinline__ unsigned short f2bf_bits(float f){
  __hip_bfloat16 h = __float2bfloat16(f);           // RNE
  return *(unsigned short*)&h;
}
static __device__ __forceinline__ us8 pack8(float4 f0, float4 f1){
  us8 w;
  w[0]=f2bf_bits(f0.x); w[1]=f2bf_bits(f0.y); w[2]=f2bf_bits(f0.z); w[3]=f2bf_bits(f0.w);
  w[4]=f2bf_bits(f1.x); w[5]=f2bf_bits(f1.y); w[6]=f2bf_bits(f1.z); w[7]=f2bf_bits(f1.w);
  return w;
}

// ---------------------------------------------------------------------------
// MFMA GEMM #1: C(bf16) = A(fp32) * B(fp32)^T.  (unchanged, passing)
// ---------------------------------------------------------------------------
__global__ __launch_bounds__(256) void gemm_qkv_mfma(const float* __restrict__ A,
    const float* __restrict__ Bm, bf16* __restrict__ Cm, int M, int Nd, int K)
{
  __shared__ short Als[128][72];
  __shared__ short Bls[128][72];
  const int m0 = blockIdx.y * 128, n0 = blockIdx.x * 128;
  const int tid = threadIdx.x;
  const int lane = tid & 63, wid = tid >> 6;
  const int wr = wid >> 1, wc = wid & 1;
  const int fr = lane & 15, hi = lane >> 4;
  const int Mrem = M - m0;
  f32x4 acc[4][4] = {};
  for (int k0 = 0; k0 < K; k0 += 64) {
    #pragma unroll
    for (int i = tid; i < 1024; i += 256) {
      int r = i >> 3, c8 = i & 7;
      us8 w = {0,0,0,0,0,0,0,0};
      if (r < Mrem) {
        const float* src = &A[(size_t)(m0 + r)*K + k0 + c8*8];
        w = pack8(ld4(src), ld4(src+4));
      }
      *(us8*)&Als[r][c8*8] = w;
    }
    #pragma unroll
    for (int i = tid; i < 1024; i += 256) {
      int r = i >> 3, c8 = i & 7;
      const float* src = &Bm[(size_t)(n0 + r)*K + k0 + c8*8];
      *(us8*)&Bls[r][c8*8] = pack8(ld4(src), ld4(src+4));
    }
    __syncthreads();
    #pragma unroll
    for (int kk = 0; kk < 64; kk += 32) {
      bf16x8 a[4], b[4];
      #pragma unroll
      for (int mi = 0; mi < 4; mi++) a[mi] = *(bf16x8*)&Als[wr*64 + mi*16 + fr][kk + hi*8];
      #pragma unroll
      for (int ni = 0; ni < 4; ni++) b[ni] = *(bf16x8*)&Bls[wc*64 + ni*16 + fr][kk + hi*8];
      #pragma unroll
      for (int mi = 0; mi < 4; mi++)
        #pragma unroll
        for (int ni = 0; ni < 4; ni++)
          acc[mi][ni] = __builtin_amdgcn_mfma_f32_16x16x32_bf16(a[mi], b[ni], acc[mi][ni], 0, 0, 0);
    }
    __syncthreads();
  }
  #pragma unroll
  for (int mi = 0; mi < 4; mi++) {
    #pragma unroll
    for (int j = 0; j < 4; j++) {
      int r = wr*64 + mi*16 + hi*4 + j;
      if (m0 + r < M) {
        #pragma unroll
        for (int ni = 0; ni < 4; ni++) {
          int cidx = n0 + wc*64 + ni*16 + fr;
          Cm[(size_t)(m0+r)*Nd + cidx] = __float2bfloat16(acc[mi][ni][j]);
        }
      }
    }
  }
}

// ---------------------------------------------------------------------------
// MFMA GEMM #2: C(fp32) = A(bf16) * B(fp32)^T + bias.  (unchanged, passing)
// ---------------------------------------------------------------------------
__global__ __launch_bounds__(256) void gemm_proj_mfma(const bf16* __restrict__ A,
    const float* __restrict__ Bm, const float* __restrict__ bias,
    float* __restrict__ Cm, int M, int Nd, int K)
{
  __shared__ short Als[128][72];
  __shared__ short Bls[128][72];
  const int m0 = blockIdx.y * 128, n0 = blockIdx.x * 128;
  const int tid = threadIdx.x;
  const int lane = tid & 63, wid = tid >> 6;
  const int wr = wid >> 1, wc = wid & 1;
  const int fr = lane & 15, hi = lane >> 4;
  const int Mrem = M - m0;
  f32x4 acc[4][4] = {};
  for (int k0 = 0; k0 < K; k0 += 64) {
    #pragma unroll
    for (int i = tid; i < 1024; i += 256) {
      int r = i >> 3, c8 = i & 7;
      us8 w = {0,0,0,0,0,0,0,0};
      if (r < Mrem) w = *(const us8*)&A[(size_t)(m0 + r)*K + k0 + c8*8];
      *(us8*)&Als[r][c8*8] = w;
    }
    #pragma unroll
    for (int i = tid; i < 1024; i += 256) {
      int r = i >> 3, c8 = i & 7;
      const float* src = &Bm[(size_t)(n0 + r)*K + k0 + c8*8];
      *(us8*)&Bls[r][c8*8] = pack8(ld4(src), ld4(src+4));
    }
    __syncthreads();
    #pragma unroll
    for (int kk = 0; kk < 64; kk += 32) {
      bf16x8 a[4], b[4];
      #pragma unroll
      for (int mi = 0; mi < 4; mi++) a[mi] = *(bf16x8*)&Als[wr*64 + mi*16 + fr][kk + hi*8];
      #pragma unroll
      for (int ni = 0; ni < 4; ni++) b[ni] = *(bf16x8*)&Bls[wc*64 + ni*16 + fr][kk + hi*8];
      #pragma unroll
      for (int mi = 0; mi < 4; mi++)
        #pragma unroll
        for (int ni = 0; ni < 4; ni++)
          acc[mi][ni] = __builtin_amdgcn_mfma_f32_16x16x32_bf16(a[mi], b[ni], acc[mi][ni], 0, 0, 0);
    }
    __syncthreads();
  }
  #pragma unroll
  for (int mi = 0; mi < 4; mi++) {
    #pragma unroll
    for (int j = 0; j < 4; j++) {
      int r = wr*64 + mi*16 + hi*4 + j;
      if (m0 + r < M) {
        #pragma unroll
        for (int ni = 0; ni < 4; ni++) {
          int cidx = n0 + wc*64 + ni*16 + fr;
          Cm[(size_t)(m0+r)*Nd + cidx] = acc[mi][ni][j] + bias[cidx];
        }
      }
    }
  }
}

// ---------------------------------------------------------------------------
// Channel attention (unchanged, passing).
// ---------------------------------------------------------------------------
__global__ __launch_bounds__(256) void chan_attn_k(const bf16* __restrict__ QKV,
                                                   float* __restrict__ attn_c)
{
  const int site = blockIdx.x;            // (b*H + h)*N + n
  const int n = site % NN; const int bh = site / NN;
  const int h = bh % HH;   const int b  = bh / HH;
  __shared__ float qs[CC*HD], ks[CC*HD], ls[CC*CC];
  const int tid = threadIdx.x;
  const size_t rowbase = (size_t)(b*NN + n) * CC;
  for (int i = tid; i < CC*HD; i += 256) {
    int c = i >> 6, d = i & 63;
    size_t idx = (rowbase + c)*E5 + h*HD + d;
    qs[i] = __bfloat162float(QKV[idx]);
    ks[i] = __bfloat162float(QKV[idx + DD]);
  }
  __syncthreads();
  if (tid < CC*CC) {
    int q = tid / CC, k = tid % CC;
    float s = 0.f;
    #pragma unroll
    for (int d = 0; d < HD; d++) s += qs[q*HD+d]*ks[k*HD+d];
    ls[tid] = s * 0.125f;
  }
  __syncthreads();
  if (tid < CC) {
    int q = tid;
    float m = -1e30f;
    #pragma unroll
    for (int k = 0; k < CC; k++) m = fmaxf(m, ls[q*CC+k]);
    float e[CC]; float sum = 0.f;
    #pragma unroll
    for (int k = 0; k < CC; k++) { e[k] = __expf(ls[q*CC+k]-m); sum += e[k]; }
    float inv = 1.f/sum;
    size_t base = (size_t)site*CC*CC + (size_t)q*CC;
    #pragma unroll
    for (int k = 0; k < CC; k++) attn_c[base+k] = e[k]*inv;
  }
}

// ---------------------------------------------------------------------------
// Spatial attention, MFMA version.
// Per block: site (b,h,y), 64-row x-tile (4 waves, 16 rows each).
// S[x][n] = Qs[x,:]*Ks[n,:] via mfma (A=Q rows, B=K rows, NT like the GEMMs).
// Softmax over n with col>=196 masked to -inf; writes bf16 rows padded to
// KP=224 (masked cols give exp->0, providing the zero padding pv_mfma needs).
// LDS rows stride 72 shorts (144B) -> the proven 2-way-max bank pattern.
// ---------------------------------------------------------------------------
__global__ __launch_bounds__(256) void spat_attn_mfma(const bf16* __restrict__ QKV,
                                                      bf16* __restrict__ attn_s)
{
  const int site = blockIdx.x;     // (b*H+h)*C + y
  const int y = site % CC; const int bh = site / CC;
  const int h = bh % HH;   const int b  = bh / HH;
  const int x0 = blockIdx.y * 64;
  __shared__ short Qls[64][72];    // 9.2 KB
  __shared__ short Kls[KP][72];    // 32.2 KB
  const int tid = threadIdx.x;
  const int lane = tid & 63, w = tid >> 6;
  const int fr = lane & 15, hi = lane >> 4;

  for (int i = tid; i < 64*8; i += 256) {        // Q tile: rows x0..x0+63
    int r = i >> 3, c8 = i & 7;
    int x = x0 + r;
    us8 v = {0,0,0,0,0,0,0,0};
    if (x < NN) v = *(const us8*)&QKV[((size_t)(b*NN + x)*CC + y)*E5 + 2*DD + h*HD + c8*8];
    *(us8*)&Qls[r][c8*8] = v;
  }
  for (int i = tid; i < KP*8; i += 256) {        // K: all rows (padded with 0)
    int r = i >> 3, c8 = i & 7;
    us8 v = {0,0,0,0,0,0,0,0};
    if (r < NN) v = *(const us8*)&QKV[((size_t)(b*NN + r)*CC + y)*E5 + 3*DD + h*HD + c8*8];
    *(us8*)&Kls[r][c8*8] = v;
  }
  __syncthreads();

  f32x4 acc[14] = {};
  #pragma unroll
  for (int kk = 0; kk < 64; kk += 32) {
    bf16x8 a = *(bf16x8*)&Qls[w*16 + fr][kk + hi*8];
    #pragma unroll
    for (int ni = 0; ni < 14; ni++) {
      bf16x8 bv = *(bf16x8*)&Kls[ni*16 + fr][kk + hi*8];
      acc[ni] = __builtin_amdgcn_mfma_f32_16x16x32_bf16(a, bv, acc[ni], 0, 0, 0);
    }
  }

  // scale + mask invalid cols (col = ni*16 + fr; same validity for all j)
  #pragma unroll
  for (int ni = 0; ni < 14; ni++) {
    bool valid = (ni*16 + fr) < NN;
    #pragma unroll
    for (int j = 0; j < 4; j++)
      acc[ni][j] = valid ? acc[ni][j]*0.125f : -1e30f;
  }
  // per-row softmax: row = x0 + w*16 + hi*4 + j; reduce over ni then fr-lanes
  #pragma unroll
  for (int j = 0; j < 4; j++) {
    float m = -1e30f;
    #pragma unroll
    for (int ni = 0; ni < 14; ni++) m = fmaxf(m, acc[ni][j]);
    #pragma unroll
    for (int s = 1; s < 16; s <<= 1) m = fmaxf(m, __shfl_xor(m, s));
    float e[14]; float sum = 0.f;
    #pragma unroll
    for (int ni = 0; ni < 14; ni++) { e[ni] = __expf(acc[ni][j] - m); sum += e[ni]; }
    #pragma unroll
    for (int s = 1; s < 16; s <<= 1) sum += __shfl_xor(sum, s);
    float inv = 1.f/sum;
    int x = x0 + w*16 + hi*4 + j;
    if (x < NN) {
      size_t base = ((size_t)site*NN + x)*KP;
      #pragma unroll
      for (int ni = 0; ni < 14; ni++)
        attn_s[base + ni*16 + fr] = __float2bfloat16(e[ni]*inv);   // masked -> 0
    }
  }
}

// ---------------------------------------------------------------------------
// V transpose: Vt[(b*H+h)*C + c][d(=64)][n(=224, zero-padded)] bf16.
// (unchanged, passing)
// ---------------------------------------------------------------------------
__global__ __launch_bounds__(256) void v_transpose_k(const bf16* __restrict__ QKV,
                                                     bf16* __restrict__ Vt)
{
  const int bhc = blockIdx.x;         // ((b*H+h)*C + c)
  const int c = bhc % CC; const int bh = bhc / CC;
  const int h = bh % HH;  const int b  = bh / HH;
  __shared__ short T[196][72];        // [n][d], padded stride
  const int tid = threadIdx.x;
  for (int i = tid; i < 196*8; i += 256) {
    int n = i >> 3, c8 = i & 7;
    us8 v = *(const us8*)&QKV[((size_t)b*NCH + c*NN + n)*E5 + 4*DD + h*HD + c8*8];
    *(us8*)&T[n][c8*8] = v;
  }
  __syncthreads();
  const size_t obase = (size_t)bhc * HD * KP;
  for (int i = tid; i < 64*28; i += 256) {
    int d = i / 28, n8 = i % 28;
    us8 w;
    #pragma unroll
    for (int j = 0; j < 8; j++) {
      int n = n8*8 + j;
      w[j] = (n < NN) ? (unsigned short)T[n][d] : (unsigned short)0;
    }
    *(us8*)&Vt[obase + (size_t)d*KP + n8*8] = w;
  }
}

// ---------------------------------------------------------------------------
// PV + channel combine, MFMA version. (unchanged, passing)
// ---------------------------------------------------------------------------
__global__ __launch_bounds__(256) void pv_mfma_k(const bf16* __restrict__ Vt,
    const bf16* __restrict__ attn_s, const float* __restrict__ attn_c,
    bf16* __restrict__ outa)
{
  const int site = blockIdx.x;     // (b*H+h)*C + y
  const int y = site % CC; const int bh = site / CC;
  const int h = bh % HH;   const int b  = bh / HH;
  const int x0 = blockIdx.y * 64;
  __shared__ short Sls[64][232];   // row 464B: 16B-aligned, ~4-way banks on b128
  __shared__ short Vls[64][232];
  __shared__ float AC[64][CC];
  const int tid = threadIdx.x;
  const int lane = tid & 63, w = tid >> 6;
  const int fr = lane & 15, hi = lane >> 4;

  for (int i = tid; i < 64*28; i += 256) {
    int r = i / 28, k8 = i % 28;
    int x = x0 + r;
    us8 v = {0,0,0,0,0,0,0,0};
    if (x < NN) v = *(const us8*)&attn_s[((size_t)site*NN + x)*KP + k8*8];
    *(us8*)&Sls[r][k8*8] = v;
  }
  for (int i = tid; i < 64*CC; i += 256) {
    int r = i / CC, c = i % CC;
    int x = x0 + r;
    AC[r][c] = (x < NN) ? attn_c[(((size_t)bh*NN + x)*CC + y)*CC + c] : 0.f;
  }

  f32x4 oacc[4] = {};
  for (int c = 0; c < CC; c++) {
    __syncthreads();                       // prev-c MFMA reads done (also covers S/AC on c=0)
    const size_t vbase = (size_t)(bh*CC + c) * HD * KP;
    for (int i = tid; i < 64*28; i += 256) {
      int d = i / 28, k8 = i % 28;
      *(us8*)&Vls[d][k8*8] = *(const us8*)&Vt[vbase + (size_t)d*KP + k8*8];
    }
    __syncthreads();
    f32x4 tacc[4] = {};
    #pragma unroll
    for (int kk = 0; kk < KP; kk += 32) {
      bf16x8 a = *(bf16x8*)&Sls[w*16 + fr][kk + hi*8];
      #pragma unroll
      for (int ni = 0; ni < 4; ni++) {
        bf16x8 bv = *(bf16x8*)&Vls[ni*16 + fr][kk + hi*8];
        tacc[ni] = __builtin_amdgcn_mfma_f32_16x16x32_bf16(a, bv, tacc[ni], 0, 0, 0);
      }
    }
    #pragma unroll
    for (int j = 0; j < 4; j++) {
      float ac = AC[w*16 + hi*4 + j][c];   // broadcast across fr lanes
      #pragma unroll
      for (int ni = 0; ni < 4; ni++) oacc[ni][j] += ac * tacc[ni][j];
    }
  }
  #pragma unroll
  for (int j = 0; j < 4; j++) {
    int x = x0 + w*16 + hi*4 + j;
    if (x < NN) {
      size_t base = ((size_t)(b*NN + x)*CC + y)*DD + h*HD;
      #pragma unroll
      for (int ni = 0; ni < 4; ni++)
        outa[base + ni*16 + fr] = __float2bfloat16(oacc[ni][j]);
    }
  }
}

// ---------------------------------------------------------------------------
// Workspace: qkv bf16 78.3MB | attn_c f32 6.4MB | attn_s bf16(224) 54.8MB
// | Vt bf16 17.9MB | outa bf16 15.7MB  => ~173MB (known-good from round 6)
// ---------------------------------------------------------------------------
extern "C" void kernel_launch(void* const* d_in, const int* in_sizes, int n_in,
                              void* d_out, int out_size, void* d_ws, size_t ws_size,
                              hipStream_t stream)
{
  const float* x     = (const float*)d_in[0];
  const float* Wqkv  = (const float*)d_in[1];
  const float* Wproj = (const float*)d_in[2];
  const float* bproj = (const float*)d_in[3];
  float* out = (float*)d_out;

  bf16*  qkv    = (bf16*)d_ws;                                    // RR*E5
  float* attn_c = (float*)(qkv + (size_t)RR*E5);                  // B*H*N*C*C
  bf16*  attn_s = (bf16*)(attn_c + (size_t)BB*HH*NN*CC*CC);       // 624*196*KP
  bf16*  Vt     = attn_s + (size_t)BB*HH*CC*NN*KP;                // 624*64*KP
  bf16*  outa   = Vt     + (size_t)BB*HH*CC*HD*KP;                // RR*DD

  // 1) QKV GEMM (MFMA)
  gemm_qkv_mfma<<<dim3(E5/128, (RR+127)/128), 256, 0, stream>>>(x, Wqkv, qkv, RR, E5, DD);
  // 2) channel attention
  chan_attn_k<<<dim3(BB*HH*NN), 256, 0, stream>>>(qkv, attn_c);
  // 3) spatial attention (MFMA, padded-row output)
  spat_attn_mfma<<<dim3(BB*HH*CC, 4), 256, 0, stream>>>(qkv, attn_s);
  // 4) V transpose for MFMA B-operand
  v_transpose_k<<<dim3(BB*HH*CC), 256, 0, stream>>>(qkv, Vt);
  // 5) PV + combine (MFMA)
  pv_mfma_k<<<dim3(BB*HH*CC, 4), 256, 0, stream>>>(Vt, attn_s, attn_c, outa);
  // 6) projection GEMM (MFMA) + bias
  gemm_proj_mfma<<<dim3(DD/128, (RR+127)/128), 256, 0, stream>>>(outa, Wproj, bproj, out, RR, DD, DD);
}

// Round 9
// 496.643 us; speedup vs baseline: 6.5315x; 1.3171x over previous
//
#include <hip/hip_runtime.h>
#include <hip/hip_bf16.h>

#define BB 4
#define NN 196
#define CC 13
#define DD 768
#define HH 12
#define HD 64
#define RR (BB*NN*CC)      /* 10192 */
#define E5 (5*DD)          /* 3840  */
#define NCH (NN*CC)        /* 2548  */
#define KP 224             /* padded spatial-K (196 -> 224, 7x32) */

typedef __hip_bfloat16 bf16;
typedef __attribute__((ext_vector_type(8))) short bf16x8;   // MFMA A/B frag (4 VGPR)
typedef __attribute__((ext_vector_type(4))) float f32x4;    // MFMA C/D frag
typedef __attribute__((ext_vector_type(8))) unsigned short us8;

static __device__ __forceinline__ float4 ld4(const float* p){ return *(const float4*)p; }
static __device__ __forceinline__ unsigned short f2bf_bits(float f){
  __hip_bfloat16 h = __float2bfloat16(f);           // RNE
  return *(unsigned short*)&h;
}
static __device__ __forceinline__ us8 pack8(float4 f0, float4 f1){
  us8 w;
  w[0]=f2bf_bits(f0.x); w[1]=f2bf_bits(f0.y); w[2]=f2bf_bits(f0.z); w[3]=f2bf_bits(f0.w);
  w[4]=f2bf_bits(f1.x); w[5]=f2bf_bits(f1.y); w[6]=f2bf_bits(f1.z); w[7]=f2bf_bits(f1.w);
  return w;
}

// ---------------------------------------------------------------------------
// fp32 -> bf16 elementwise convert (n multiple of 8). Hoists the RNE
// conversion the GEMMs previously did per-tile (numerics identical).
// ---------------------------------------------------------------------------
__global__ __launch_bounds__(256) void cvt_bf16_k(const float* __restrict__ in,
                                                  bf16* __restrict__ outb, int n8)
{
  for (int i = blockIdx.x*256 + threadIdx.x; i < n8; i += gridDim.x*256) {
    const float* src = in + (size_t)i*8;
    *(us8*)&outb[(size_t)i*8] = pack8(ld4(src), ld4(src+4));
  }
}

// ---------------------------------------------------------------------------
// GEMM (all-bf16): C(bf16) = A * B^T.  A: MxK, B: NdxK row-major bf16.
// BM=BN=128, BK=64, 4 waves, wave -> 64x64 (4x4 frags of 16x16x32).
// ---------------------------------------------------------------------------
__global__ __launch_bounds__(256) void gemm_qkv_bb(const bf16* __restrict__ A,
    const bf16* __restrict__ Bm, bf16* __restrict__ Cm, int M, int Nd, int K)
{
  __shared__ short Als[128][72];
  __shared__ short Bls[128][72];
  const int m0 = blockIdx.y * 128, n0 = blockIdx.x * 128;
  const int tid = threadIdx.x;
  const int lane = tid & 63, wid = tid >> 6;
  const int wr = wid >> 1, wc = wid & 1;
  const int fr = lane & 15, hi = lane >> 4;
  const int Mrem = M - m0;
  f32x4 acc[4][4] = {};
  for (int k0 = 0; k0 < K; k0 += 64) {
    #pragma unroll
    for (int i = tid; i < 1024; i += 256) {
      int r = i >> 3, c8 = i & 7;
      us8 w = {0,0,0,0,0,0,0,0};
      if (r < Mrem) w = *(const us8*)&A[(size_t)(m0 + r)*K + k0 + c8*8];
      *(us8*)&Als[r][c8*8] = w;
    }
    #pragma unroll
    for (int i = tid; i < 1024; i += 256) {
      int r = i >> 3, c8 = i & 7;
      *(us8*)&Bls[r][c8*8] = *(const us8*)&Bm[(size_t)(n0 + r)*K + k0 + c8*8];
    }
    __syncthreads();
    #pragma unroll
    for (int kk = 0; kk < 64; kk += 32) {
      bf16x8 a[4], b[4];
      #pragma unroll
      for (int mi = 0; mi < 4; mi++) a[mi] = *(bf16x8*)&Als[wr*64 + mi*16 + fr][kk + hi*8];
      #pragma unroll
      for (int ni = 0; ni < 4; ni++) b[ni] = *(bf16x8*)&Bls[wc*64 + ni*16 + fr][kk + hi*8];
      #pragma unroll
      for (int mi = 0; mi < 4; mi++)
        #pragma unroll
        for (int ni = 0; ni < 4; ni++)
          acc[mi][ni] = __builtin_amdgcn_mfma_f32_16x16x32_bf16(a[mi], b[ni], acc[mi][ni], 0, 0, 0);
    }
    __syncthreads();
  }
  #pragma unroll
  for (int mi = 0; mi < 4; mi++) {
    #pragma unroll
    for (int j = 0; j < 4; j++) {
      int r = wr*64 + mi*16 + hi*4 + j;
      if (m0 + r < M) {
        #pragma unroll
        for (int ni = 0; ni < 4; ni++) {
          int cidx = n0 + wc*64 + ni*16 + fr;
          Cm[(size_t)(m0+r)*Nd + cidx] = __float2bfloat16(acc[mi][ni][j]);
        }
      }
    }
  }
}

// ---------------------------------------------------------------------------
// GEMM (all-bf16): C(fp32) = A * B^T + bias.
// ---------------------------------------------------------------------------
__global__ __launch_bounds__(256) void gemm_proj_bb(const bf16* __restrict__ A,
    const bf16* __restrict__ Bm, const float* __restrict__ bias,
    float* __restrict__ Cm, int M, int Nd, int K)
{
  __shared__ short Als[128][72];
  __shared__ short Bls[128][72];
  const int m0 = blockIdx.y * 128, n0 = blockIdx.x * 128;
  const int tid = threadIdx.x;
  const int lane = tid & 63, wid = tid >> 6;
  const int wr = wid >> 1, wc = wid & 1;
  const int fr = lane & 15, hi = lane >> 4;
  const int Mrem = M - m0;
  f32x4 acc[4][4] = {};
  for (int k0 = 0; k0 < K; k0 += 64) {
    #pragma unroll
    for (int i = tid; i < 1024; i += 256) {
      int r = i >> 3, c8 = i & 7;
      us8 w = {0,0,0,0,0,0,0,0};
      if (r < Mrem) w = *(const us8*)&A[(size_t)(m0 + r)*K + k0 + c8*8];
      *(us8*)&Als[r][c8*8] = w;
    }
    #pragma unroll
    for (int i = tid; i < 1024; i += 256) {
      int r = i >> 3, c8 = i & 7;
      *(us8*)&Bls[r][c8*8] = *(const us8*)&Bm[(size_t)(n0 + r)*K + k0 + c8*8];
    }
    __syncthreads();
    #pragma unroll
    for (int kk = 0; kk < 64; kk += 32) {
      bf16x8 a[4], b[4];
      #pragma unroll
      for (int mi = 0; mi < 4; mi++) a[mi] = *(bf16x8*)&Als[wr*64 + mi*16 + fr][kk + hi*8];
      #pragma unroll
      for (int ni = 0; ni < 4; ni++) b[ni] = *(bf16x8*)&Bls[wc*64 + ni*16 + fr][kk + hi*8];
      #pragma unroll
      for (int mi = 0; mi < 4; mi++)
        #pragma unroll
        for (int ni = 0; ni < 4; ni++)
          acc[mi][ni] = __builtin_amdgcn_mfma_f32_16x16x32_bf16(a[mi], b[ni], acc[mi][ni], 0, 0, 0);
    }
    __syncthreads();
  }
  #pragma unroll
  for (int mi = 0; mi < 4; mi++) {
    #pragma unroll
    for (int j = 0; j < 4; j++) {
      int r = wr*64 + mi*16 + hi*4 + j;
      if (m0 + r < M) {
        #pragma unroll
        for (int ni = 0; ni < 4; ni++) {
          int cidx = n0 + wc*64 + ni*16 + fr;
          Cm[(size_t)(m0+r)*Nd + cidx] = acc[mi][ni][j] + bias[cidx];
        }
      }
    }
  }
}

// ---------------------------------------------------------------------------
// Channel attention (unchanged, passing).
// ---------------------------------------------------------------------------
__global__ __launch_bounds__(256) void chan_attn_k(const bf16* __restrict__ QKV,
                                                   float* __restrict__ attn_c)
{
  const int site = blockIdx.x;            // (b*H + h)*N + n
  const int n = site % NN; const int bh = site / NN;
  const int h = bh % HH;   const int b  = bh / HH;
  __shared__ float qs[CC*HD], ks[CC*HD], ls[CC*CC];
  const int tid = threadIdx.x;
  const size_t rowbase = (size_t)(b*NN + n) * CC;
  for (int i = tid; i < CC*HD; i += 256) {
    int c = i >> 6, d = i & 63;
    size_t idx = (rowbase + c)*E5 + h*HD + d;
    qs[i] = __bfloat162float(QKV[idx]);
    ks[i] = __bfloat162float(QKV[idx + DD]);
  }
  __syncthreads();
  if (tid < CC*CC) {
    int q = tid / CC, k = tid % CC;
    float s = 0.f;
    #pragma unroll
    for (int d = 0; d < HD; d++) s += qs[q*HD+d]*ks[k*HD+d];
    ls[tid] = s * 0.125f;
  }
  __syncthreads();
  if (tid < CC) {
    int q = tid;
    float m = -1e30f;
    #pragma unroll
    for (int k = 0; k < CC; k++) m = fmaxf(m, ls[q*CC+k]);
    float e[CC]; float sum = 0.f;
    #pragma unroll
    for (int k = 0; k < CC; k++) { e[k] = __expf(ls[q*CC+k]-m); sum += e[k]; }
    float inv = 1.f/sum;
    size_t base = (size_t)site*CC*CC + (size_t)q*CC;
    #pragma unroll
    for (int k = 0; k < CC; k++) attn_c[base+k] = e[k]*inv;
  }
}

// ---------------------------------------------------------------------------
// Spatial attention, MFMA version (unchanged, passing).
// ---------------------------------------------------------------------------
__global__ __launch_bounds__(256) void spat_attn_mfma(const bf16* __restrict__ QKV,
                                                      bf16* __restrict__ attn_s)
{
  const int site = blockIdx.x;     // (b*H+h)*C + y
  const int y = site % CC; const int bh = site / CC;
  const int h = bh % HH;   const int b  = bh / HH;
  const int x0 = blockIdx.y * 64;
  __shared__ short Qls[64][72];
  __shared__ short Kls[KP][72];
  const int tid = threadIdx.x;
  const int lane = tid & 63, w = tid >> 6;
  const int fr = lane & 15, hi = lane >> 4;

  for (int i = tid; i < 64*8; i += 256) {
    int r = i >> 3, c8 = i & 7;
    int x = x0 + r;
    us8 v = {0,0,0,0,0,0,0,0};
    if (x < NN) v = *(const us8*)&QKV[((size_t)(b*NN + x)*CC + y)*E5 + 2*DD + h*HD + c8*8];
    *(us8*)&Qls[r][c8*8] = v;
  }
  for (int i = tid; i < KP*8; i += 256) {
    int r = i >> 3, c8 = i & 7;
    us8 v = {0,0,0,0,0,0,0,0};
    if (r < NN) v = *(const us8*)&QKV[((size_t)(b*NN + r)*CC + y)*E5 + 3*DD + h*HD + c8*8];
    *(us8*)&Kls[r][c8*8] = v;
  }
  __syncthreads();

  f32x4 acc[14] = {};
  #pragma unroll
  for (int kk = 0; kk < 64; kk += 32) {
    bf16x8 a = *(bf16x8*)&Qls[w*16 + fr][kk + hi*8];
    #pragma unroll
    for (int ni = 0; ni < 14; ni++) {
      bf16x8 bv = *(bf16x8*)&Kls[ni*16 + fr][kk + hi*8];
      acc[ni] = __builtin_amdgcn_mfma_f32_16x16x32_bf16(a, bv, acc[ni], 0, 0, 0);
    }
  }

  #pragma unroll
  for (int ni = 0; ni < 14; ni++) {
    bool valid = (ni*16 + fr) < NN;
    #pragma unroll
    for (int j = 0; j < 4; j++)
      acc[ni][j] = valid ? acc[ni][j]*0.125f : -1e30f;
  }
  #pragma unroll
  for (int j = 0; j < 4; j++) {
    float m = -1e30f;
    #pragma unroll
    for (int ni = 0; ni < 14; ni++) m = fmaxf(m, acc[ni][j]);
    #pragma unroll
    for (int s = 1; s < 16; s <<= 1) m = fmaxf(m, __shfl_xor(m, s));
    float e[14]; float sum = 0.f;
    #pragma unroll
    for (int ni = 0; ni < 14; ni++) { e[ni] = __expf(acc[ni][j] - m); sum += e[ni]; }
    #pragma unroll
    for (int s = 1; s < 16; s <<= 1) sum += __shfl_xor(sum, s);
    float inv = 1.f/sum;
    int x = x0 + w*16 + hi*4 + j;
    if (x < NN) {
      size_t base = ((size_t)site*NN + x)*KP;
      #pragma unroll
      for (int ni = 0; ni < 14; ni++)
        attn_s[base + ni*16 + fr] = __float2bfloat16(e[ni]*inv);   // masked -> 0
    }
  }
}

// ---------------------------------------------------------------------------
// V transpose (unchanged, passing).
// ---------------------------------------------------------------------------
__global__ __launch_bounds__(256) void v_transpose_k(const bf16* __restrict__ QKV,
                                                     bf16* __restrict__ Vt)
{
  const int bhc = blockIdx.x;         // ((b*H+h)*C + c)
  const int c = bhc % CC; const int bh = bhc / CC;
  const int h = bh % HH;  const int b  = bh / HH;
  __shared__ short T[196][72];
  const int tid = threadIdx.x;
  for (int i = tid; i < 196*8; i += 256) {
    int n = i >> 3, c8 = i & 7;
    us8 v = *(const us8*)&QKV[((size_t)b*NCH + c*NN + n)*E5 + 4*DD + h*HD + c8*8];
    *(us8*)&T[n][c8*8] = v;
  }
  __syncthreads();
  const size_t obase = (size_t)bhc * HD * KP;
  for (int i = tid; i < 64*28; i += 256) {
    int d = i / 28, n8 = i % 28;
    us8 w;
    #pragma unroll
    for (int j = 0; j < 8; j++) {
      int n = n8*8 + j;
      w[j] = (n < NN) ? (unsigned short)T[n][d] : (unsigned short)0;
    }
    *(us8*)&Vt[obase + (size_t)d*KP + n8*8] = w;
  }
}

// ---------------------------------------------------------------------------
// PV + channel combine, v2.
// (a) XCD-aware bijective swizzle: all 52 blocks (13 y x 4 x-tiles) of one bh
//     land on one XCD -> Vt[bh] (373 KB) stays L2-resident.
//     j -> r=j%8, k=j/8: bh = r + 8*(k/52); y=(k%52)/4; xt=k%4.  (48 bh = 8*6)
// (b) S-fragments are wave-private -> loaded once from global into 7 bf16x8
//     regs; Sls LDS + its barriers eliminated (LDS 63->33 KB, 4 blocks/CU).
// ---------------------------------------------------------------------------
__global__ __launch_bounds__(256) void pv_mfma2_k(const bf16* __restrict__ Vt,
    const bf16* __restrict__ attn_s, const float* __restrict__ attn_c,
    bf16* __restrict__ outa)
{
  const int j0 = blockIdx.x;
  const int r  = j0 & 7, k = j0 >> 3;
  const int bh = r + 8*(k/52);
  const int rem = k % 52;
  const int y  = rem >> 2;
  const int x0 = (rem & 3) * 64;
  const int h = bh % HH, b = bh / HH;
  const int site = bh*CC + y;

  __shared__ short Vls[64][232];
  __shared__ float AC[64][CC];
  const int tid = threadIdx.x;
  const int lane = tid & 63, w = tid >> 6;
  const int fr = lane & 15, hi = lane >> 4;

  // A-fragments (wave-private S rows) straight from global; OOB rows (x>=196)
  // read adjacent mapped ws memory and produce discarded D rows.
  bf16x8 aS[7];
  {
    const bf16* srow = &attn_s[((size_t)site*NN + x0 + w*16 + fr)*KP];
    #pragma unroll
    for (int t = 0; t < 7; t++) aS[t] = *(const bf16x8*)&srow[t*32 + hi*8];
  }
  for (int i = tid; i < 64*CC; i += 256) {
    int rr = i / CC, c = i % CC;
    int x = x0 + rr;
    AC[rr][c] = (x < NN) ? attn_c[(((size_t)bh*NN + x)*CC + y)*CC + c] : 0.f;
  }

  f32x4 oacc[4] = {};
  for (int c = 0; c < CC; c++) {
    __syncthreads();                       // prev-c Vls reads done (c=0: AC visible)
    const size_t vbase = (size_t)(bh*CC + c) * HD * KP;
    for (int i = tid; i < 64*28; i += 256) {
      int d = i / 28, k8 = i % 28;
      *(us8*)&Vls[d][k8*8] = *(const us8*)&Vt[vbase + (size_t)d*KP + k8*8];
    }
    __syncthreads();
    f32x4 tacc[4] = {};
    #pragma unroll
    for (int t = 0; t < 7; t++) {
      #pragma unroll
      for (int ni = 0; ni < 4; ni++) {
        bf16x8 bv = *(bf16x8*)&Vls[ni*16 + fr][t*32 + hi*8];
        tacc[ni] = __builtin_amdgcn_mfma_f32_16x16x32_bf16(aS[t], bv, tacc[ni], 0, 0, 0);
      }
    }
    #pragma unroll
    for (int jj = 0; jj < 4; jj++) {
      float ac = AC[w*16 + hi*4 + jj][c];
      #pragma unroll
      for (int ni = 0; ni < 4; ni++) oacc[ni][jj] += ac * tacc[ni][jj];
    }
  }
  #pragma unroll
  for (int jj = 0; jj < 4; jj++) {
    int x = x0 + w*16 + hi*4 + jj;
    if (x < NN) {
      size_t base = ((size_t)(b*NN + x)*CC + y)*DD + h*HD;
      #pragma unroll
      for (int ni = 0; ni < 4; ni++)
        outa[base + ni*16 + fr] = __float2bfloat16(oacc[ni][jj]);
    }
  }
}

// ---------------------------------------------------------------------------
// Workspace: qkv 78.3 | attn_c 6.4 | attn_s 54.8 (xb aliases: 15.7, dead
// after qkv GEMM) | Vt 17.9 (qb aliases: 5.9, dead after qkv GEMM) |
// outa 15.7 | pb 1.2  => ~174.3 MB (round-6 passed at 173 MB).
// ---------------------------------------------------------------------------
extern "C" void kernel_launch(void* const* d_in, const int* in_sizes, int n_in,
                              void* d_out, int out_size, void* d_ws, size_t ws_size,
                              hipStream_t stream)
{
  const float* x     = (const float*)d_in[0];
  const float* Wqkv  = (const float*)d_in[1];
  const float* Wproj = (const float*)d_in[2];
  const float* bproj = (const float*)d_in[3];
  float* out = (float*)d_out;

  bf16*  qkv    = (bf16*)d_ws;                                    // RR*E5
  float* attn_c = (float*)(qkv + (size_t)RR*E5);                  // B*H*N*C*C
  bf16*  attn_s = (bf16*)(attn_c + (size_t)BB*HH*NN*CC*CC);       // 624*196*KP
  bf16*  Vt     = attn_s + (size_t)BB*HH*CC*NN*KP;                // 624*64*KP
  bf16*  outa   = Vt     + (size_t)BB*HH*CC*HD*KP;                // RR*DD
  bf16*  pb     = outa   + (size_t)RR*DD;                         // DD*DD
  bf16*  xb     = attn_s;   // alias: dead before spat_attn writes attn_s
  bf16*  qb     = Vt;       // alias: dead before v_transpose writes Vt

  // 0) hoisted fp32->bf16 converts (same RNE rounding as before)
  cvt_bf16_k<<<dim3(1024), 256, 0, stream>>>(x,     xb, RR*DD/8);
  cvt_bf16_k<<<dim3(1024), 256, 0, stream>>>(Wqkv,  qb, E5*DD/8);
  cvt_bf16_k<<<dim3(288),  256, 0, stream>>>(Wproj, pb, DD*DD/8);
  // 1) QKV GEMM (bf16 x bf16)
  gemm_qkv_bb<<<dim3(E5/128, (RR+127)/128), 256, 0, stream>>>(xb, qb, qkv, RR, E5, DD);
  // 2) channel attention
  chan_attn_k<<<dim3(BB*HH*NN), 256, 0, stream>>>(qkv, attn_c);
  // 3) spatial attention (MFMA, padded rows; clobbers xb - dead)
  spat_attn_mfma<<<dim3(BB*HH*CC, 4), 256, 0, stream>>>(qkv, attn_s);
  // 4) V transpose (clobbers qb - dead)
  v_transpose_k<<<dim3(BB*HH*CC), 256, 0, stream>>>(qkv, Vt);
  // 5) PV + combine v2 (XCD-swizzled, reg-resident S-frags)
  pv_mfma2_k<<<dim3(BB*HH*CC*4), 256, 0, stream>>>(Vt, attn_s, attn_c, outa);
  // 6) projection GEMM + bias
  gemm_proj_bb<<<dim3(DD/128, (RR+127)/128), 256, 0, stream>>>(outa, pb, bproj, out, RR, DD, DD);
}